// Round 1
// 8216.073 us; speedup vs baseline: 1.7087x; 1.7087x over previous
//
#include <hip/hip_runtime.h>
#include <hip/hip_bf16.h>
#include <hip/hip_cooperative_groups.h>
#include <cstdint>
#include <cstddef>

namespace cg = cooperative_groups;

// Problem dims
#define B_   64
#define S_   512
#define T_   256
#define E_   512
#define H_   512
#define KQ_  256
#define V_   1000

typedef unsigned short bf16_t;
typedef __attribute__((ext_vector_type(8))) short short8;   // 8 bf16 (4 VGPRs) — MFMA A/B frag
typedef __attribute__((ext_vector_type(4))) float floatx4;  // MFMA C/D frag

// ---------- small helpers ----------
static __device__ __forceinline__ float bflo(unsigned u){ unsigned x = u << 16;        return __builtin_bit_cast(float, x); }
static __device__ __forceinline__ float bfhi(unsigned u){ unsigned x = u & 0xffff0000u; return __builtin_bit_cast(float, x); }
static __device__ __forceinline__ float bf2f(bf16_t h){ unsigned x = ((unsigned)h) << 16; return __builtin_bit_cast(float, x); }
static __device__ __forceinline__ bf16_t f2bf(float f){
    unsigned u = __builtin_bit_cast(unsigned, f);
    unsigned r = u + 0x7fffu + ((u >> 16) & 1u);   // RNE
    return (bf16_t)(r >> 16);
}
static __device__ __forceinline__ float sigm(float x){ return 1.f / (1.f + __expf(-x)); }
static __device__ __forceinline__ float tanh_(float x){
    float ax = fabsf(x); float t = __expf(-2.f * ax);
    float r = (1.f - t) / (1.f + t);
    return copysignf(r, x);
}
static __device__ __forceinline__ short8 ld8(const bf16_t* p){ return *(const short8*)p; }
static __device__ __forceinline__ floatx4 mfma16(short8 a, short8 b, floatx4 c){
    return __builtin_amdgcn_mfma_f32_16x16x32_bf16(a, b, c, 0, 0, 0);
}

// Shared MFMA K-loop: 4 M-tiles (M=64) x 1 N-tile (N=16) per wave.
// A frag: A[m=lane&15][k=quad*8+j]; B frag from W rows (B^T): B[n=lane&15][k].
// D frag: row(m)=quad*4+r, col(n)=lane&15  (m89-verified convention).
static __device__ __forceinline__ void mfma_kloop(const bf16_t* const rA[4], const bf16_t* rB,
                                                  int K, int quad, floatx4 acc[4]){
    for (int ks = 0; ks < K; ks += 32){
        int ko = ks + quad * 8;
        short8 bf = ld8(rB + ko);
        #pragma unroll
        for (int mi = 0; mi < 4; ++mi)
            acc[mi] = mfma16(ld8(rA[mi] + ko), bf, acc[mi]);
    }
}

// ---------- one-time conversion kernel ----------
// Segments (element index): Wcat1 | Wcat2 | emb(pad 1024 rows) | W1 | WqT | Wkv | enc | bcat1 | bcat2 | bkv
#define CV_E0 2097152UL
#define CV_E1 4194304UL
#define CV_E2 4718592UL
#define CV_E3 5242880UL
#define CV_E4 5373952UL
#define CV_E5 5767168UL
#define CV_E6 22544384UL
#define CV_E7 22546432UL
#define CV_E8 22548480UL
#define CV_E9 22549248UL

__global__ __launch_bounds__(256) void convert_kernel(
    const float* __restrict__ enc,  const float* __restrict__ Wemb,
    const float* __restrict__ Wih1, const float* __restrict__ Whh1,
    const float* __restrict__ Wih2, const float* __restrict__ Whh2,
    const float* __restrict__ Wq,   const float* __restrict__ Wk,
    const float* __restrict__ Wv,   const float* __restrict__ W1,
    const float* __restrict__ bih1, const float* __restrict__ bhh1,
    const float* __restrict__ bih2, const float* __restrict__ bhh2,
    const float* __restrict__ bk,   const float* __restrict__ bv,
    bf16_t* __restrict__ Wc1,  bf16_t* __restrict__ Wc2, bf16_t* __restrict__ emb16,
    bf16_t* __restrict__ W116, bf16_t* __restrict__ WqT16, bf16_t* __restrict__ Wkv16,
    bf16_t* __restrict__ enc16, float* __restrict__ bcat1, float* __restrict__ bcat2,
    float* __restrict__ bkvO)
{
    for (size_t i = (size_t)blockIdx.x * 256 + threadIdx.x; i < CV_E9; i += (size_t)gridDim.x * 256){
        if (i < CV_E0){ size_t r = i >> 10, k = i & 1023;
            float v_ = (k < 512) ? Wih1[r*512 + k] : Whh1[r*512 + (k - 512)];
            Wc1[i] = f2bf(v_);
        } else if (i < CV_E1){ size_t l = i - CV_E0, r = l >> 10, k = l & 1023;
            float v_ = (k < 512) ? Wih2[r*512 + k] : Whh2[r*512 + (k - 512)];
            Wc2[l] = f2bf(v_);
        } else if (i < CV_E2){ size_t l = i - CV_E1, r = l >> 9, k = l & 511;
            emb16[l] = f2bf(r < 1000 ? Wemb[r*512 + k] : 0.f);
        } else if (i < CV_E3){ size_t l = i - CV_E2;
            W116[l] = f2bf(W1[l]);
        } else if (i < CV_E4){ size_t l = i - CV_E3, h = l >> 8, nn = l & 255;
            WqT16[l] = f2bf(Wq[nn*512 + h]);     // WqT[h][d] = Wq[d][h]
        } else if (i < CV_E5){ size_t l = i - CV_E4, r = l >> 9, k = l & 511;
            float v_ = (r < 256) ? Wk[r*512 + k] : Wv[(r - 256)*512 + k];
            Wkv16[l] = f2bf(v_);
        } else if (i < CV_E6){ size_t l = i - CV_E5;
            enc16[l] = f2bf(enc[l]);
        } else if (i < CV_E7){ size_t l = i - CV_E6; bcat1[l] = bih1[l] + bhh1[l]; }
        else if (i < CV_E8){ size_t l = i - CV_E7; bcat2[l] = bih2[l] + bhh2[l]; }
        else { size_t l = i - CV_E8; bkvO[l] = (l < 256) ? bk[l] : bv[l - 256]; }
    }
}

// ---------- k/v projection: [k|v](m,n) = enc(m,:) . Wkv(n,:) + bkv(n);  M=32768, N=768, K=512 ----------
// k output row-major [b*512+s][256]; v output TRANSPOSED per batch: vT[b][e][s] (via LDS tile transpose)
// so the ctx MFMA B-operand (rows indexed by e, contiguous in s) reads coalesced.
__global__ __launch_bounds__(256) void gemm_kv_kernel(
    const bf16_t* __restrict__ enc16, const bf16_t* __restrict__ Wkv16,
    const float* __restrict__ bkv, bf16_t* __restrict__ kq16, bf16_t* __restrict__ vT16)
{
    __shared__ bf16_t tile[64][72];   // 64 m(s) x 64 n(e), pad 72 vs bank conflicts
    const int tid = threadIdx.x, lane = tid & 63, wv = tid >> 6, ml = lane & 15, quad = lane >> 4;
    const int mb = blockIdx.x, nb = blockIdx.y;
    const int n = nb*64 + wv*16 + ml;
    const bf16_t* brow = Wkv16 + (size_t)n * 512;
    const bf16_t* rA[4];
    #pragma unroll
    for (int mi = 0; mi < 4; ++mi) rA[mi] = enc16 + (size_t)(mb*64 + mi*16 + ml) * 512;
    floatx4 acc[4];
    #pragma unroll
    for (int mi = 0; mi < 4; ++mi) acc[mi] = (floatx4){0.f, 0.f, 0.f, 0.f};
    mfma_kloop(rA, brow, 512, quad, acc);
    const float bias = bkv[n];
    if (nb < 4){
        #pragma unroll
        for (int mi = 0; mi < 4; ++mi)
            #pragma unroll
            for (int r = 0; r < 4; ++r){
                int m = mb*64 + mi*16 + quad*4 + r;
                kq16[(size_t)m*256 + n] = f2bf(acc[mi][r] + bias);
            }
    } else {
        #pragma unroll
        for (int mi = 0; mi < 4; ++mi)
            #pragma unroll
            for (int r = 0; r < 4; ++r)
                tile[mi*16 + quad*4 + r][wv*16 + ml] = f2bf(acc[mi][r] + bias);
        __syncthreads();
        const int b = mb >> 3, s0 = (mb & 7) * 64, e0 = nb*64 - 256;
        const int eloc = tid >> 2, sc = (tid & 3) * 16;
        bf16_t* dst = vT16 + ((size_t)(b*512 + e0 + eloc)) * 512 + s0 + sc;
        #pragma unroll
        for (int j = 0; j < 16; ++j) dst[j] = tile[sc + j][eloc];
    }
}

// ---------- k2 = k @ Wq: M=32768, N=512, K=256 ----------
__global__ __launch_bounds__(256) void gemm_k2_kernel(
    const bf16_t* __restrict__ kq16, const bf16_t* __restrict__ WqT16, bf16_t* __restrict__ k216)
{
    const int tid = threadIdx.x, lane = tid & 63, wv = tid >> 6, ml = lane & 15, quad = lane >> 4;
    const int mb = blockIdx.x, nb = blockIdx.y;
    const int n = nb*64 + wv*16 + ml;
    const bf16_t* brow = WqT16 + (size_t)n * 256;
    const bf16_t* rA[4];
    #pragma unroll
    for (int mi = 0; mi < 4; ++mi) rA[mi] = kq16 + (size_t)(mb*64 + mi*16 + ml) * 256;
    floatx4 acc[4];
    #pragma unroll
    for (int mi = 0; mi < 4; ++mi) acc[mi] = (floatx4){0.f, 0.f, 0.f, 0.f};
    mfma_kloop(rA, brow, 256, quad, acc);
    #pragma unroll
    for (int mi = 0; mi < 4; ++mi)
        #pragma unroll
        for (int r = 0; r < 4; ++r){
            int m = mb*64 + mi*16 + quad*4 + r;
            k216[(size_t)m*512 + n] = f2bf(acc[mi][r]);
        }
}

// ---------- kb[m] = k[m,:] . bq ----------
__global__ __launch_bounds__(256) void kbias_kernel(
    const bf16_t* __restrict__ kq16, const float* __restrict__ bq, float* __restrict__ kb)
{
    int m = blockIdx.x * 256 + threadIdx.x;  // 32768 total
    const unsigned* row = (const unsigned*)(kq16 + (size_t)m * 256);
    float acc = 0.f;
    #pragma unroll 8
    for (int i = 0; i < 128; ++i){
        unsigned u = row[i];
        acc += bflo(u) * bq[2*i] + bfhi(u) * bq[2*i + 1];
    }
    kb[m] = acc;
}

// ---------- LSTM cell, 8-wave variant: waves (gate g, K-half kh). K-half 0 = x@Wih, 1 = h@Whh ----------
// smemf layout: [8 waves][64 rows][17] floats (pad 17 breaks bank conflicts)
#define LG(w_, b_, j_) smemf[((w_)*64 + (b_))*17 + (j_)]
static __device__ __forceinline__ void lstm_part2(
    int tid, int jblk,
    const bf16_t* __restrict__ xrows, const bf16_t* __restrict__ emb,
    const int* __restrict__ y, int tok_col, int use_emb,
    const bf16_t* __restrict__ h_in, bf16_t* __restrict__ h_out,
    float* __restrict__ c_st, const bf16_t* __restrict__ Wcat,
    const float* __restrict__ bcat, bf16_t* __restrict__ arch,  // arch: h2all + t*512, row stride T_*512
    float* smemf)
{
    const int lane = tid & 63, w = tid >> 6, ml = lane & 15, quad = lane >> 4;
    const int g = w & 3, kh = w >> 2;
    const int j0 = jblk * 16;
    const bf16_t* brow = Wcat + (size_t)(g*512 + j0 + ml) * 1024 + (size_t)kh * 512;
    const bf16_t* rA[4];
    #pragma unroll
    for (int mi = 0; mi < 4; ++mi){
        int b = mi*16 + ml;
        if (kh == 0){
            if (use_emb){
                int tok = (tok_col < 0) ? 0 : y[b * T_ + tok_col];   // SOS=0
                rA[mi] = emb + (size_t)tok * 512;
            } else rA[mi] = xrows + (size_t)b * 512;
        } else {
            rA[mi] = h_in + (size_t)b * 512;
        }
    }
    floatx4 acc[4];
    #pragma unroll
    for (int mi = 0; mi < 4; ++mi) acc[mi] = (floatx4){0.f, 0.f, 0.f, 0.f};
    for (int ks = 0; ks < 512; ks += 32){
        int ko = ks + quad * 8;
        short8 bf = ld8(brow + ko);
        #pragma unroll
        for (int mi = 0; mi < 4; ++mi) acc[mi] = mfma16(ld8(rA[mi] + ko), bf, acc[mi]);
    }
    #pragma unroll
    for (int mi = 0; mi < 4; ++mi)
        #pragma unroll
        for (int r = 0; r < 4; ++r)
            LG(w, mi*16 + quad*4 + r, ml) = acc[mi][r];
    __syncthreads();
    // cell update: 512 threads x 2 cells (64 b x 16 j)
    const int jj = tid & 15, b0 = tid >> 4;  // b0 in [0,32)
    const int j = j0 + jj;
    const float bi = bcat[j], bff = bcat[512 + j], bg = bcat[1024 + j], bo = bcat[1536 + j];
    #pragma unroll
    for (int c = 0; c < 2; ++c){
        int b = b0 + 32 * c;
        float gi = LG(0, b, jj) + LG(4, b, jj) + bi;
        float gf = LG(1, b, jj) + LG(5, b, jj) + bff;
        float gg = LG(2, b, jj) + LG(6, b, jj) + bg;
        float go = LG(3, b, jj) + LG(7, b, jj) + bo;
        size_t idx = (size_t)b * 512 + j;
        float cn = sigm(gf) * c_st[idx] + sigm(gi) * tanh_(gg);
        float hn = sigm(go) * tanh_(cn);
        c_st[idx] = cn;
        bf16_t hb = f2bf(hn);
        h_out[idx] = hb;
        if (arch) arch[(size_t)b * ((size_t)T_ * 512) + j] = hb;  // h2all[b*T+t][j]
    }
}

// ---------- cooperative scan: ONLY the recurrent LSTM chain (attention never feeds back) ----------
// Period p: LSTM1(t=p) on blocks 0..31 | LSTM2(t=p-1) on blocks 32..63 (archives h2(t) to h2all).
// Grid = 64 blocks -> cheap grid sync; per-period traffic = L2-resident weight slices only.
struct ScanParams {
    const int* y;
    const bf16_t *emb16, *Wc1, *Wc2;
    const float *bcat1, *bcat2;
    bf16_t *h1, *h2, *h2all;
    float *c1, *c2;
};

#define SPER (T_ + 1)   // 257 periods

__global__ __launch_bounds__(512, 2) void scan_kernel(ScanParams P)
{
    cg::grid_group gg = cg::this_grid();
    __shared__ __align__(16) float smemf[8704];
    const int bx = blockIdx.x, tid = threadIdx.x;
    const size_t BH = (size_t)B_ * H_;

    for (int p = 0; p < SPER; ++p){
        if (bx < 32){
            int t = p;
            if (t < T_){
                lstm_part2(tid, bx, nullptr, P.emb16, P.y, t - 1, 1,
                           P.h1 + ((t - 1) & 1) * BH, P.h1 + (t & 1) * BH,
                           P.c1, P.Wc1, P.bcat1, nullptr, smemf);
            }
        } else {
            int t = p - 1;
            if (t >= 0){
                lstm_part2(tid, bx - 32, P.h1 + (t & 1) * BH, nullptr, nullptr, 0, 0,
                           P.h2 + ((t - 1) & 1) * BH, P.h2 + (t & 1) * BH,
                           P.c2, P.Wc2, P.bcat2, P.h2all + (size_t)t * 512, smemf);
            }
        }
        gg.sync();
    }
}

// ---------- batched post-scan stages (fully parallel over all 16384 (b,t) rows) ----------

// raw[b*T+t][s] = (h2all[b*T+t] . k2[b][s] + kb[b][s]) / 16;  per batch: M=256, N=512, K=512
__global__ __launch_bounds__(256) void scores_kernel(
    const bf16_t* __restrict__ h2all, const bf16_t* __restrict__ k216,
    const float* __restrict__ kb, float* __restrict__ raw)
{
    const int tid = threadIdx.x, lane = tid & 63, wv = tid >> 6, ml = lane & 15, quad = lane >> 4;
    const int nt = blockIdx.x, mt = blockIdx.y, b = blockIdx.z;
    const int n = nt*64 + wv*16 + ml;            // s
    const bf16_t* brow = k216 + ((size_t)b*512 + n) * 512;
    const bf16_t* rA[4];
    #pragma unroll
    for (int mi = 0; mi < 4; ++mi)
        rA[mi] = h2all + ((size_t)b*T_ + mt*64 + mi*16 + ml) * 512;
    floatx4 acc[4];
    #pragma unroll
    for (int mi = 0; mi < 4; ++mi) acc[mi] = (floatx4){0.f, 0.f, 0.f, 0.f};
    mfma_kloop(rA, brow, 512, quad, acc);
    const float kbn = kb[(size_t)b*512 + n];
    #pragma unroll
    for (int mi = 0; mi < 4; ++mi)
        #pragma unroll
        for (int r = 0; r < 4; ++r){
            int m = mt*64 + mi*16 + quad*4 + r;  // t
            raw[((size_t)b*T_ + m)*512 + n] = (acc[mi][r] + kbn) * 0.0625f;
        }
}

// softmax over s for each of the 16384 rows; writes out_attn (f32) and attn split hi/lo bf16
// (hi+lo two-term split keeps ctx accumulation at f32-attn accuracy through the bf16 MFMA).
__global__ __launch_bounds__(512) void softmax_kernel(
    const float* __restrict__ raw, float* __restrict__ out_attn,
    bf16_t* __restrict__ attnb, bf16_t* __restrict__ attnlo)
{
    __shared__ float red[16];
    const int tid = threadIdx.x;
    const size_t r = blockIdx.x;
    float sc = raw[r*512 + tid];
    float mx = sc;
    #pragma unroll
    for (int o = 32; o > 0; o >>= 1) mx = fmaxf(mx, __shfl_xor(mx, o, 64));
    if ((tid & 63) == 0) red[tid >> 6] = mx;
    __syncthreads();
    float gmax = red[0];
    #pragma unroll
    for (int i = 1; i < 8; ++i) gmax = fmaxf(gmax, red[i]);
    float e = __expf(sc - gmax);
    float sm = e;
    #pragma unroll
    for (int o = 32; o > 0; o >>= 1) sm += __shfl_xor(sm, o, 64);
    if ((tid & 63) == 0) red[8 + (tid >> 6)] = sm;
    __syncthreads();
    float tot = red[8];
    #pragma unroll
    for (int i = 1; i < 8; ++i) tot += red[8 + i];
    float attn = e / tot;
    out_attn[r*512 + tid] = attn;
    bf16_t hi = f2bf(attn);
    attnb [r*512 + tid] = hi;
    attnlo[r*512 + tid] = f2bf(attn - bf2f(hi));
}

// ctx[b*T+t][e] = sum_s attn[b,t,s] * v[b,s,e];  A = attn hi/lo rows, B-rows = vT[b][e][:]
__global__ __launch_bounds__(256) void ctx_kernel(
    const bf16_t* __restrict__ attnb, const bf16_t* __restrict__ attnlo,
    const bf16_t* __restrict__ vT16, bf16_t* __restrict__ ctxb)
{
    const int tid = threadIdx.x, lane = tid & 63, wv = tid >> 6, ml = lane & 15, quad = lane >> 4;
    const int nt = blockIdx.x, mt = blockIdx.y, b = blockIdx.z;
    const int n = nt*64 + wv*16 + ml;            // e
    const bf16_t* brow = vT16 + ((size_t)b*512 + n) * 512;
    const bf16_t* rA[4]; const bf16_t* rAlo[4];
    #pragma unroll
    for (int mi = 0; mi < 4; ++mi){
        size_t row = (size_t)b*T_ + mt*64 + mi*16 + ml;
        rA[mi]   = attnb  + row * 512;
        rAlo[mi] = attnlo + row * 512;
    }
    floatx4 acc[4];
    #pragma unroll
    for (int mi = 0; mi < 4; ++mi) acc[mi] = (floatx4){0.f, 0.f, 0.f, 0.f};
    mfma_kloop(rA,   brow, 512, quad, acc);
    mfma_kloop(rAlo, brow, 512, quad, acc);
    #pragma unroll
    for (int mi = 0; mi < 4; ++mi)
        #pragma unroll
        for (int r = 0; r < 4; ++r){
            int m = mt*64 + mi*16 + quad*4 + r;  // t
            ctxb[((size_t)b*T_ + m)*512 + n] = f2bf(acc[mi][r]);
        }
}

// hid[m][n] = relu([h2all|ctx](m,:) . W1row(n,:) + b1[n]);  M=16384, N=512, K=1024 (two halves)
__global__ __launch_bounds__(512) void hid_kernel(
    const bf16_t* __restrict__ h2all, const bf16_t* __restrict__ ctxb,
    const bf16_t* __restrict__ W116, const float* __restrict__ b1, bf16_t* __restrict__ hid)
{
    const int tid = threadIdx.x, lane = tid & 63, w = tid >> 6, ml = lane & 15, quad = lane >> 4;
    const int nb = blockIdx.x, mb = blockIdx.y;
    const int n = nb*128 + w*16 + ml;
    const bf16_t* brow = W116 + (size_t)n * 1024;
    const bf16_t* rA[4]; const bf16_t* rC[4];
    #pragma unroll
    for (int mi = 0; mi < 4; ++mi){
        size_t m = (size_t)(mb*64 + mi*16 + ml);
        rA[mi] = h2all + m * 512;
        rC[mi] = ctxb  + m * 512;
    }
    floatx4 acc[4];
    #pragma unroll
    for (int mi = 0; mi < 4; ++mi) acc[mi] = (floatx4){0.f, 0.f, 0.f, 0.f};
    mfma_kloop(rA, brow,       512, quad, acc);
    mfma_kloop(rC, brow + 512, 512, quad, acc);
    const float bias = b1[n];
    #pragma unroll
    for (int mi = 0; mi < 4; ++mi)
        #pragma unroll
        for (int r = 0; r < 4; ++r){
            int m = mb*64 + mi*16 + quad*4 + r;
            hid[(size_t)m*512 + n] = f2bf(fmaxf(acc[mi][r] + bias, 0.f));
        }
}

// out_logits[m][n] = hid(m,:) . emb(n,:) + bcls[n];  M=16384, N=1024(pad of 1000), K=512
__global__ __launch_bounds__(512) void logits_kernel(
    const bf16_t* __restrict__ hid, const bf16_t* __restrict__ emb16,
    const float* __restrict__ bcls, float* __restrict__ out_logits)
{
    const int tid = threadIdx.x, lane = tid & 63, w = tid >> 6, ml = lane & 15, quad = lane >> 4;
    const int nb = blockIdx.x, mb = blockIdx.y;
    const int n = nb*128 + w*16 + ml;
    const bf16_t* brow = emb16 + (size_t)n * 512;
    const bf16_t* rA[4];
    #pragma unroll
    for (int mi = 0; mi < 4; ++mi) rA[mi] = hid + (size_t)(mb*64 + mi*16 + ml) * 512;
    floatx4 acc[4];
    #pragma unroll
    for (int mi = 0; mi < 4; ++mi) acc[mi] = (floatx4){0.f, 0.f, 0.f, 0.f};
    mfma_kloop(rA, brow, 512, quad, acc);
    if (n < V_){
        const float bias = bcls[n];
        #pragma unroll
        for (int mi = 0; mi < 4; ++mi)
            #pragma unroll
            for (int r = 0; r < 4; ++r){
                int m = mb*64 + mi*16 + quad*4 + r;
                out_logits[(size_t)m * V_ + n] = acc[mi][r] + bias;
            }
    }
}

// ---------------------------------------------------------------------------
extern "C" void kernel_launch(void* const* d_in, const int* in_sizes, int n_in,
                              void* d_out, int out_size, void* d_ws, size_t ws_size,
                              hipStream_t stream)
{
    const float* enc  = (const float*)d_in[0];
    const int*   y    = (const int*)  d_in[1];
    const float* Wemb = (const float*)d_in[2];
    const float* Wih1 = (const float*)d_in[3];  const float* bih1 = (const float*)d_in[4];
    const float* Whh1 = (const float*)d_in[5];  const float* bhh1 = (const float*)d_in[6];
    const float* Wih2 = (const float*)d_in[7];  const float* bih2 = (const float*)d_in[8];
    const float* Whh2 = (const float*)d_in[9];  const float* bhh2 = (const float*)d_in[10];
    const float* Wq   = (const float*)d_in[11]; const float* bq   = (const float*)d_in[12];
    const float* Wk   = (const float*)d_in[13]; const float* bk   = (const float*)d_in[14];
    const float* Wv   = (const float*)d_in[15]; const float* bv   = (const float*)d_in[16];
    const float* W1   = (const float*)d_in[17]; const float* b1   = (const float*)d_in[18];
    const float* bcls = (const float*)d_in[19];

    float* outF = (float*)d_out;
    float* out_logits = outF;
    float* out_attn   = outF + (size_t)B_ * T_ * V_;

    // workspace carve (256B aligned). Peak ~96 MB (same as previous version) via aliasing:
    //  Region A (33.5MB): enc16 -> k216 -> attn hi/lo
    //  Region B (16.8MB): kq16 -> h2all
    //  Region C (33.5MB): vT   -> hid
    //  out_logits region (65.5MB) doubles as scratch: raw scores [0,33.5) then ctxb [33.5,50.3)
    size_t off = 0;
    char* wsb = (char*)d_ws;
    auto carve = [&](size_t bytes) -> void* {
        void* p = wsb + off;
        off += (bytes + 255) & ~(size_t)255;
        return p;
    };
    bf16_t* enc16 = (bf16_t*)carve((size_t)B_*S_*E_*2);     // Region A
    bf16_t* k216  = enc16;
    bf16_t* attnb = enc16;                                   // 16.8MB
    bf16_t* attnlo= enc16 + (size_t)B_*T_*S_;                // +16.8MB = 33.5MB exact
    bf16_t* kq16  = (bf16_t*)carve((size_t)B_*S_*KQ_*2);    // Region B
    bf16_t* h2all = kq16;                                    // B*T*H*2 = 16.8MB exact
    bf16_t* vT16  = (bf16_t*)carve((size_t)B_*S_*E_*2);     // Region C
    bf16_t* hid   = vT16;                                    // 16.8MB <= 33.5MB
    bf16_t* Wc1   = (bf16_t*)carve((size_t)2048*1024*2);
    bf16_t* Wc2   = (bf16_t*)carve((size_t)2048*1024*2);
    bf16_t* emb16 = (bf16_t*)carve((size_t)1024*512*2);     // padded to 1024 rows
    bf16_t* W116  = (bf16_t*)carve((size_t)512*1024*2);
    bf16_t* WqT16 = (bf16_t*)carve((size_t)512*256*2);
    bf16_t* Wkv16 = (bf16_t*)carve((size_t)768*512*2);
    float*  bcat1 = (float*) carve(2048*4);
    float*  bcat2 = (float*) carve(2048*4);
    float*  bkv   = (float*) carve(768*4);
    float*  kb    = (float*) carve((size_t)B_*S_*4);        // 128 KB
    bf16_t* h1b   = (bf16_t*)carve((size_t)2*B_*H_*2);      // ping-pong
    bf16_t* h2b   = (bf16_t*)carve((size_t)2*B_*H_*2);
    float*  c1    = (float*) carve((size_t)B_*H_*4);
    float*  c2    = (float*) carve((size_t)B_*H_*4);

    float*  raw   = out_logits;                              // [16384][512] f32 scratch in out region
    bf16_t* ctxb  = (bf16_t*)((char*)out_logits + (size_t)B_*T_*S_*4);  // next 16.8MB of out region

    // zero recurrent state (ws is poisoned before every call)
    hipMemsetAsync(h1b, 0, (size_t)2*B_*H_*2, stream);
    hipMemsetAsync(h2b, 0, (size_t)2*B_*H_*2, stream);
    hipMemsetAsync(c1,  0, (size_t)B_*H_*4, stream);
    hipMemsetAsync(c2,  0, (size_t)B_*H_*4, stream);

    // setup: convert weights/enc, project k/v (v transposed), fold Wq into k2, bq into kb
    convert_kernel<<<8192, 256, 0, stream>>>(enc, Wemb, Wih1, Whh1, Wih2, Whh2, Wq, Wk, Wv, W1,
                                             bih1, bhh1, bih2, bhh2, bk, bv,
                                             Wc1, Wc2, emb16, W116, WqT16, Wkv16, enc16,
                                             bcat1, bcat2, bkv);
    gemm_kv_kernel<<<dim3(512, 12), 256, 0, stream>>>(enc16, Wkv16, bkv, kq16, vT16);
    gemm_k2_kernel<<<dim3(512, 8), 256, 0, stream>>>(kq16, WqT16, k216);
    kbias_kernel<<<128, 256, 0, stream>>>(kq16, bq, kb);

    // sequential part: ONLY the LSTM chain (64-block cooperative kernel, 257 grid syncs)
    ScanParams sp;
    sp.y = y; sp.emb16 = emb16; sp.Wc1 = Wc1; sp.Wc2 = Wc2;
    sp.bcat1 = bcat1; sp.bcat2 = bcat2;
    sp.h1 = h1b; sp.h2 = h2b; sp.h2all = h2all;
    sp.c1 = c1; sp.c2 = c2;
    void* kargs[] = { (void*)&sp };
    hipLaunchCooperativeKernel((const void*)scan_kernel, dim3(64), dim3(512), kargs, 0, stream);

    // batch-parallel tail: scores -> softmax -> ctx -> hid -> logits
    scores_kernel <<<dim3(8, 4, B_), 256, 0, stream>>>(h2all, k216, kb, raw);
    softmax_kernel<<<(size_t)B_*T_, 512, 0, stream>>>(raw, out_attn, attnb, attnlo);
    ctx_kernel    <<<dim3(8, 4, B_), 256, 0, stream>>>(attnb, attnlo, vT16, ctxb);
    hid_kernel    <<<dim3(4, 256), 512, 0, stream>>>(h2all, ctxb, W116, b1, hid);
    logits_kernel <<<dim3(8, 256), 512, 0, stream>>>(hid, emb16, bcls, out_logits);
}

// Round 2
// 7341.803 us; speedup vs baseline: 1.9121x; 1.1191x over previous
//
#include <hip/hip_runtime.h>
#include <hip/hip_bf16.h>
#include <hip/hip_cooperative_groups.h>
#include <cstdint>
#include <cstddef>

namespace cg = cooperative_groups;

// Problem dims
#define B_   64
#define S_   512
#define T_   256
#define E_   512
#define H_   512
#define KQ_  256
#define V_   1000

typedef unsigned short bf16_t;
typedef __attribute__((ext_vector_type(8))) short short8;   // 8 bf16 (4 VGPRs) — MFMA A/B frag
typedef __attribute__((ext_vector_type(4))) float floatx4;  // MFMA C/D frag

// ---------- small helpers ----------
static __device__ __forceinline__ float bflo(unsigned u){ unsigned x = u << 16;        return __builtin_bit_cast(float, x); }
static __device__ __forceinline__ float bfhi(unsigned u){ unsigned x = u & 0xffff0000u; return __builtin_bit_cast(float, x); }
static __device__ __forceinline__ float bf2f(bf16_t h){ unsigned x = ((unsigned)h) << 16; return __builtin_bit_cast(float, x); }
static __device__ __forceinline__ bf16_t f2bf(float f){
    unsigned u = __builtin_bit_cast(unsigned, f);
    unsigned r = u + 0x7fffu + ((u >> 16) & 1u);   // RNE
    return (bf16_t)(r >> 16);
}
static __device__ __forceinline__ float sigm(float x){ return 1.f / (1.f + __expf(-x)); }
static __device__ __forceinline__ float tanh_(float x){
    float ax = fabsf(x); float t = __expf(-2.f * ax);
    float r = (1.f - t) / (1.f + t);
    return copysignf(r, x);
}
static __device__ __forceinline__ short8 ld8(const bf16_t* p){ return *(const short8*)p; }
static __device__ __forceinline__ floatx4 mfma16(short8 a, short8 b, floatx4 c){
    return __builtin_amdgcn_mfma_f32_16x16x32_bf16(a, b, c, 0, 0, 0);
}

// Shared MFMA K-loop: 4 M-tiles (M=64) x 1 N-tile (N=16) per wave.
// A frag: A[m=lane&15][k=quad*8+j]; B frag from W rows (B^T): B[n=lane&15][k].
// D frag: row(m)=quad*4+r, col(n)=lane&15  (m89-verified convention).
static __device__ __forceinline__ void mfma_kloop(const bf16_t* const rA[4], const bf16_t* rB,
                                                  int K, int quad, floatx4 acc[4]){
    for (int ks = 0; ks < K; ks += 32){
        int ko = ks + quad * 8;
        short8 bf = ld8(rB + ko);
        #pragma unroll
        for (int mi = 0; mi < 4; ++mi)
            acc[mi] = mfma16(ld8(rA[mi] + ko), bf, acc[mi]);
    }
}

// ---------- one-time conversion kernel ----------
// Segments (element index): Wcat1 | Wcat2 | emb(pad 1024 rows) | W1 | WqT | Wkv | enc | bcat1 | bcat2 | bkv
#define CV_E0 2097152UL
#define CV_E1 4194304UL
#define CV_E2 4718592UL
#define CV_E3 5242880UL
#define CV_E4 5373952UL
#define CV_E5 5767168UL
#define CV_E6 22544384UL
#define CV_E7 22546432UL
#define CV_E8 22548480UL
#define CV_E9 22549248UL

__global__ __launch_bounds__(256) void convert_kernel(
    const float* __restrict__ enc,  const float* __restrict__ Wemb,
    const float* __restrict__ Wih1, const float* __restrict__ Whh1,
    const float* __restrict__ Wih2, const float* __restrict__ Whh2,
    const float* __restrict__ Wq,   const float* __restrict__ Wk,
    const float* __restrict__ Wv,   const float* __restrict__ W1,
    const float* __restrict__ bih1, const float* __restrict__ bhh1,
    const float* __restrict__ bih2, const float* __restrict__ bhh2,
    const float* __restrict__ bk,   const float* __restrict__ bv,
    bf16_t* __restrict__ Wc1,  bf16_t* __restrict__ Wc2, bf16_t* __restrict__ emb16,
    bf16_t* __restrict__ W116, bf16_t* __restrict__ WqT16, bf16_t* __restrict__ Wkv16,
    bf16_t* __restrict__ enc16, float* __restrict__ bcat1, float* __restrict__ bcat2,
    float* __restrict__ bkvO)
{
    for (size_t i = (size_t)blockIdx.x * 256 + threadIdx.x; i < CV_E9; i += (size_t)gridDim.x * 256){
        if (i < CV_E0){ size_t r = i >> 10, k = i & 1023;
            float v_ = (k < 512) ? Wih1[r*512 + k] : Whh1[r*512 + (k - 512)];
            Wc1[i] = f2bf(v_);
        } else if (i < CV_E1){ size_t l = i - CV_E0, r = l >> 10, k = l & 1023;
            float v_ = (k < 512) ? Wih2[r*512 + k] : Whh2[r*512 + (k - 512)];
            Wc2[l] = f2bf(v_);
        } else if (i < CV_E2){ size_t l = i - CV_E1, r = l >> 9, k = l & 511;
            emb16[l] = f2bf(r < 1000 ? Wemb[r*512 + k] : 0.f);
        } else if (i < CV_E3){ size_t l = i - CV_E2;
            W116[l] = f2bf(W1[l]);
        } else if (i < CV_E4){ size_t l = i - CV_E3, h = l >> 8, nn = l & 255;
            WqT16[l] = f2bf(Wq[nn*512 + h]);     // WqT[h][d] = Wq[d][h]
        } else if (i < CV_E5){ size_t l = i - CV_E4, r = l >> 9, k = l & 511;
            float v_ = (r < 256) ? Wk[r*512 + k] : Wv[(r - 256)*512 + k];
            Wkv16[l] = f2bf(v_);
        } else if (i < CV_E6){ size_t l = i - CV_E5;
            enc16[l] = f2bf(enc[l]);
        } else if (i < CV_E7){ size_t l = i - CV_E6; bcat1[l] = bih1[l] + bhh1[l]; }
        else if (i < CV_E8){ size_t l = i - CV_E7; bcat2[l] = bih2[l] + bhh2[l]; }
        else { size_t l = i - CV_E8; bkvO[l] = (l < 256) ? bk[l] : bv[l - 256]; }
    }
}

// ---------- k/v projection: [k|v](m,n) = enc(m,:) . Wkv(n,:) + bkv(n);  M=32768, N=768, K=512 ----------
// k output row-major [b*512+s][256]; v output TRANSPOSED per batch: vT[b][e][s] (via LDS tile transpose)
// so the ctx MFMA B-operand (rows indexed by e, contiguous in s) reads coalesced.
__global__ __launch_bounds__(256) void gemm_kv_kernel(
    const bf16_t* __restrict__ enc16, const bf16_t* __restrict__ Wkv16,
    const float* __restrict__ bkv, bf16_t* __restrict__ kq16, bf16_t* __restrict__ vT16)
{
    __shared__ bf16_t tile[64][72];   // 64 m(s) x 64 n(e), pad 72 vs bank conflicts
    const int tid = threadIdx.x, lane = tid & 63, wv = tid >> 6, ml = lane & 15, quad = lane >> 4;
    const int mb = blockIdx.x, nb = blockIdx.y;
    const int n = nb*64 + wv*16 + ml;
    const bf16_t* brow = Wkv16 + (size_t)n * 512;
    const bf16_t* rA[4];
    #pragma unroll
    for (int mi = 0; mi < 4; ++mi) rA[mi] = enc16 + (size_t)(mb*64 + mi*16 + ml) * 512;
    floatx4 acc[4];
    #pragma unroll
    for (int mi = 0; mi < 4; ++mi) acc[mi] = (floatx4){0.f, 0.f, 0.f, 0.f};
    mfma_kloop(rA, brow, 512, quad, acc);
    const float bias = bkv[n];
    if (nb < 4){
        #pragma unroll
        for (int mi = 0; mi < 4; ++mi)
            #pragma unroll
            for (int r = 0; r < 4; ++r){
                int m = mb*64 + mi*16 + quad*4 + r;
                kq16[(size_t)m*256 + n] = f2bf(acc[mi][r] + bias);
            }
    } else {
        #pragma unroll
        for (int mi = 0; mi < 4; ++mi)
            #pragma unroll
            for (int r = 0; r < 4; ++r)
                tile[mi*16 + quad*4 + r][wv*16 + ml] = f2bf(acc[mi][r] + bias);
        __syncthreads();
        const int b = mb >> 3, s0 = (mb & 7) * 64, e0 = nb*64 - 256;
        const int eloc = tid >> 2, sc = (tid & 3) * 16;
        bf16_t* dst = vT16 + ((size_t)(b*512 + e0 + eloc)) * 512 + s0 + sc;
        #pragma unroll
        for (int j = 0; j < 16; ++j) dst[j] = tile[sc + j][eloc];
    }
}

// ---------- k2 = k @ Wq: M=32768, N=512, K=256 ----------
__global__ __launch_bounds__(256) void gemm_k2_kernel(
    const bf16_t* __restrict__ kq16, const bf16_t* __restrict__ WqT16, bf16_t* __restrict__ k216)
{
    const int tid = threadIdx.x, lane = tid & 63, wv = tid >> 6, ml = lane & 15, quad = lane >> 4;
    const int mb = blockIdx.x, nb = blockIdx.y;
    const int n = nb*64 + wv*16 + ml;
    const bf16_t* brow = WqT16 + (size_t)n * 256;
    const bf16_t* rA[4];
    #pragma unroll
    for (int mi = 0; mi < 4; ++mi) rA[mi] = kq16 + (size_t)(mb*64 + mi*16 + ml) * 256;
    floatx4 acc[4];
    #pragma unroll
    for (int mi = 0; mi < 4; ++mi) acc[mi] = (floatx4){0.f, 0.f, 0.f, 0.f};
    mfma_kloop(rA, brow, 256, quad, acc);
    #pragma unroll
    for (int mi = 0; mi < 4; ++mi)
        #pragma unroll
        for (int r = 0; r < 4; ++r){
            int m = mb*64 + mi*16 + quad*4 + r;
            k216[(size_t)m*512 + n] = f2bf(acc[mi][r]);
        }
}

// ---------- kb[m] = k[m,:] . bq ----------
__global__ __launch_bounds__(256) void kbias_kernel(
    const bf16_t* __restrict__ kq16, const float* __restrict__ bq, float* __restrict__ kb)
{
    int m = blockIdx.x * 256 + threadIdx.x;  // 32768 total
    const unsigned* row = (const unsigned*)(kq16 + (size_t)m * 256);
    float acc = 0.f;
    #pragma unroll 8
    for (int i = 0; i < 128; ++i){
        unsigned u = row[i];
        acc += bflo(u) * bq[2*i] + bfhi(u) * bq[2*i + 1];
    }
    kb[m] = acc;
}

// ---------- LSTM cell, 8-wave variant: waves (gate g, K-half kh). K-half 0 = x@Wih, 1 = h@Whh ----------
// smemf layout: [8 waves][64 rows][17] floats (pad 17 breaks bank conflicts)
#define LG(w_, b_, j_) smemf[((w_)*64 + (b_))*17 + (j_)]
static __device__ __forceinline__ void lstm_part2(
    int tid, int jblk,
    const bf16_t* __restrict__ xrows, const bf16_t* __restrict__ emb,
    const int* __restrict__ y, int tok_col, int use_emb,
    const bf16_t* __restrict__ h_in, bf16_t* __restrict__ h_out,
    float* __restrict__ c_st, const bf16_t* __restrict__ Wcat,
    const float* __restrict__ bcat, bf16_t* __restrict__ arch,  // arch: h2all + t*512, row stride T_*512
    float* smemf)
{
    const int lane = tid & 63, w = tid >> 6, ml = lane & 15, quad = lane >> 4;
    const int g = w & 3, kh = w >> 2;
    const int j0 = jblk * 16;
    const bf16_t* brow = Wcat + (size_t)(g*512 + j0 + ml) * 1024 + (size_t)kh * 512;
    const bf16_t* rA[4];
    #pragma unroll
    for (int mi = 0; mi < 4; ++mi){
        int b = mi*16 + ml;
        if (kh == 0){
            if (use_emb){
                int tok = (tok_col < 0) ? 0 : y[b * T_ + tok_col];   // SOS=0
                rA[mi] = emb + (size_t)tok * 512;
            } else rA[mi] = xrows + (size_t)b * 512;
        } else {
            rA[mi] = h_in + (size_t)b * 512;
        }
    }
    floatx4 acc[4];
    #pragma unroll
    for (int mi = 0; mi < 4; ++mi) acc[mi] = (floatx4){0.f, 0.f, 0.f, 0.f};
    for (int ks = 0; ks < 512; ks += 32){
        int ko = ks + quad * 8;
        short8 bf = ld8(brow + ko);
        #pragma unroll
        for (int mi = 0; mi < 4; ++mi) acc[mi] = mfma16(ld8(rA[mi] + ko), bf, acc[mi]);
    }
    #pragma unroll
    for (int mi = 0; mi < 4; ++mi)
        #pragma unroll
        for (int r = 0; r < 4; ++r)
            LG(w, mi*16 + quad*4 + r, ml) = acc[mi][r];
    __syncthreads();
    // cell update: 512 threads x 2 cells (64 b x 16 j)
    const int jj = tid & 15, b0 = tid >> 4;  // b0 in [0,32)
    const int j = j0 + jj;
    const float bi = bcat[j], bff = bcat[512 + j], bg = bcat[1024 + j], bo = bcat[1536 + j];
    #pragma unroll
    for (int c = 0; c < 2; ++c){
        int b = b0 + 32 * c;
        float gi = LG(0, b, jj) + LG(4, b, jj) + bi;
        float gf = LG(1, b, jj) + LG(5, b, jj) + bff;
        float gg = LG(2, b, jj) + LG(6, b, jj) + bg;
        float go = LG(3, b, jj) + LG(7, b, jj) + bo;
        size_t idx = (size_t)b * 512 + j;
        float cn = sigm(gf) * c_st[idx] + sigm(gi) * tanh_(gg);
        float hn = sigm(go) * tanh_(cn);
        c_st[idx] = cn;
        bf16_t hb = f2bf(hn);
        h_out[idx] = hb;
        if (arch) arch[(size_t)b * ((size_t)T_ * 512) + j] = hb;  // h2all[b*T+t][j]
    }
}

// ---------- cooperative scan: ONLY the recurrent LSTM chain (attention never feeds back) ----------
// Period p: LSTM1(t=p) on blocks 0..31 | LSTM2(t=p-1) on blocks 32..63 (archives h2(t) to h2all).
// Grid = 64 blocks. Grid barrier is HAND-ROLLED (monotonic counter, relaxed poll + s_sleep(1),
// one agent-scope acquire fence on exit) — cg::grid_group::sync's long-sleep polling and
// system-scope fences cost ~25 us/period; this is the round-2 lever.
struct ScanParams {
    const int* y;
    const bf16_t *emb16, *Wc1, *Wc2;
    const float *bcat1, *bcat2;
    bf16_t *h1, *h2, *h2all;
    float *c1, *c2;
    unsigned* bar;
};

#define SPER (T_ + 1)   // 257 periods
#define NBLK 64

__global__ __launch_bounds__(512, 2) void scan_kernel(ScanParams P)
{
    __shared__ __align__(16) float smemf[8704];
    const int bx = blockIdx.x, tid = threadIdx.x;
    const size_t BH = (size_t)B_ * H_;

    for (int p = 0; p < SPER; ++p){
        if (bx < 32){
            int t = p;
            if (t < T_){
                lstm_part2(tid, bx, nullptr, P.emb16, P.y, t - 1, 1,
                           P.h1 + ((t - 1) & 1) * BH, P.h1 + (t & 1) * BH,
                           P.c1, P.Wc1, P.bcat1, nullptr, smemf);
            }
        } else {
            int t = p - 1;
            if (t >= 0){
                lstm_part2(tid, bx - 32, P.h1 + (t & 1) * BH, nullptr, nullptr, 0, 0,
                           P.h2 + ((t - 1) & 1) * BH, P.h2 + (t & 1) * BH,
                           P.c2, P.Wc2, P.bcat2, P.h2all + (size_t)t * 512, smemf);
            }
        }
        // ---- fast grid barrier ----
        // __syncthreads drains the block's stores to L2 (compiler emits vmcnt(0) before s_barrier);
        // release-add pushes them device-visible; relaxed poll avoids per-iteration cache inv;
        // single __threadfence on exit invalidates stale L1/L2 before next period's reads.
        __syncthreads();
        if (tid == 0){
            __hip_atomic_fetch_add(P.bar, 1u, __ATOMIC_RELEASE, __HIP_MEMORY_SCOPE_AGENT);
            const unsigned tgt = (unsigned)NBLK * (unsigned)(p + 1);
            while (__hip_atomic_load(P.bar, __ATOMIC_RELAXED, __HIP_MEMORY_SCOPE_AGENT) < tgt)
                __builtin_amdgcn_s_sleep(1);
            __threadfence();
        }
        __syncthreads();
    }
}

// ---------- batched post-scan stages (fully parallel over all 16384 (b,t) rows) ----------

// raw[b*T+t][s] = (h2all[b*T+t] . k2[b][s] + kb[b][s]) / 16;  per batch: M=256, N=512, K=512
__global__ __launch_bounds__(256) void scores_kernel(
    const bf16_t* __restrict__ h2all, const bf16_t* __restrict__ k216,
    const float* __restrict__ kb, float* __restrict__ raw)
{
    const int tid = threadIdx.x, lane = tid & 63, wv = tid >> 6, ml = lane & 15, quad = lane >> 4;
    const int nt = blockIdx.x, mt = blockIdx.y, b = blockIdx.z;
    const int n = nt*64 + wv*16 + ml;            // s
    const bf16_t* brow = k216 + ((size_t)b*512 + n) * 512;
    const bf16_t* rA[4];
    #pragma unroll
    for (int mi = 0; mi < 4; ++mi)
        rA[mi] = h2all + ((size_t)b*T_ + mt*64 + mi*16 + ml) * 512;
    floatx4 acc[4];
    #pragma unroll
    for (int mi = 0; mi < 4; ++mi) acc[mi] = (floatx4){0.f, 0.f, 0.f, 0.f};
    mfma_kloop(rA, brow, 512, quad, acc);
    const float kbn = kb[(size_t)b*512 + n];
    #pragma unroll
    for (int mi = 0; mi < 4; ++mi)
        #pragma unroll
        for (int r = 0; r < 4; ++r){
            int m = mt*64 + mi*16 + quad*4 + r;  // t
            raw[((size_t)b*T_ + m)*512 + n] = (acc[mi][r] + kbn) * 0.0625f;
        }
}

// softmax over s for each of the 16384 rows; writes out_attn (f32) and attn split hi/lo bf16
// (hi+lo two-term split keeps ctx accumulation at f32-attn accuracy through the bf16 MFMA).
__global__ __launch_bounds__(512) void softmax_kernel(
    const float* __restrict__ raw, float* __restrict__ out_attn,
    bf16_t* __restrict__ attnb, bf16_t* __restrict__ attnlo)
{
    __shared__ float red[16];
    const int tid = threadIdx.x;
    const size_t r = blockIdx.x;
    float sc = raw[r*512 + tid];
    float mx = sc;
    #pragma unroll
    for (int o = 32; o > 0; o >>= 1) mx = fmaxf(mx, __shfl_xor(mx, o, 64));
    if ((tid & 63) == 0) red[tid >> 6] = mx;
    __syncthreads();
    float gmax = red[0];
    #pragma unroll
    for (int i = 1; i < 8; ++i) gmax = fmaxf(gmax, red[i]);
    float e = __expf(sc - gmax);
    float sm = e;
    #pragma unroll
    for (int o = 32; o > 0; o >>= 1) sm += __shfl_xor(sm, o, 64);
    if ((tid & 63) == 0) red[8 + (tid >> 6)] = sm;
    __syncthreads();
    float tot = red[8];
    #pragma unroll
    for (int i = 1; i < 8; ++i) tot += red[8 + i];
    float attn = e / tot;
    out_attn[r*512 + tid] = attn;
    bf16_t hi = f2bf(attn);
    attnb [r*512 + tid] = hi;
    attnlo[r*512 + tid] = f2bf(attn - bf2f(hi));
}

// ctx[b*T+t][e] = sum_s attn[b,t,s] * v[b,s,e];  A = attn hi/lo rows, B-rows = vT[b][e][:]
__global__ __launch_bounds__(256) void ctx_kernel(
    const bf16_t* __restrict__ attnb, const bf16_t* __restrict__ attnlo,
    const bf16_t* __restrict__ vT16, bf16_t* __restrict__ ctxb)
{
    const int tid = threadIdx.x, lane = tid & 63, wv = tid >> 6, ml = lane & 15, quad = lane >> 4;
    const int nt = blockIdx.x, mt = blockIdx.y, b = blockIdx.z;
    const int n = nt*64 + wv*16 + ml;            // e
    const bf16_t* brow = vT16 + ((size_t)b*512 + n) * 512;
    const bf16_t* rA[4]; const bf16_t* rAlo[4];
    #pragma unroll
    for (int mi = 0; mi < 4; ++mi){
        size_t row = (size_t)b*T_ + mt*64 + mi*16 + ml;
        rA[mi]   = attnb  + row * 512;
        rAlo[mi] = attnlo + row * 512;
    }
    floatx4 acc[4];
    #pragma unroll
    for (int mi = 0; mi < 4; ++mi) acc[mi] = (floatx4){0.f, 0.f, 0.f, 0.f};
    mfma_kloop(rA,   brow, 512, quad, acc);
    mfma_kloop(rAlo, brow, 512, quad, acc);
    #pragma unroll
    for (int mi = 0; mi < 4; ++mi)
        #pragma unroll
        for (int r = 0; r < 4; ++r){
            int m = mt*64 + mi*16 + quad*4 + r;  // t
            ctxb[((size_t)b*T_ + m)*512 + n] = f2bf(acc[mi][r]);
        }
}

// hid[m][n] = relu([h2all|ctx](m,:) . W1row(n,:) + b1[n]);  M=16384, N=512, K=1024 (two halves)
__global__ __launch_bounds__(512) void hid_kernel(
    const bf16_t* __restrict__ h2all, const bf16_t* __restrict__ ctxb,
    const bf16_t* __restrict__ W116, const float* __restrict__ b1, bf16_t* __restrict__ hid)
{
    const int tid = threadIdx.x, lane = tid & 63, w = tid >> 6, ml = lane & 15, quad = lane >> 4;
    const int nb = blockIdx.x, mb = blockIdx.y;
    const int n = nb*128 + w*16 + ml;
    const bf16_t* brow = W116 + (size_t)n * 1024;
    const bf16_t* rA[4]; const bf16_t* rC[4];
    #pragma unroll
    for (int mi = 0; mi < 4; ++mi){
        size_t m = (size_t)(mb*64 + mi*16 + ml);
        rA[mi] = h2all + m * 512;
        rC[mi] = ctxb  + m * 512;
    }
    floatx4 acc[4];
    #pragma unroll
    for (int mi = 0; mi < 4; ++mi) acc[mi] = (floatx4){0.f, 0.f, 0.f, 0.f};
    mfma_kloop(rA, brow,       512, quad, acc);
    mfma_kloop(rC, brow + 512, 512, quad, acc);
    const float bias = b1[n];
    #pragma unroll
    for (int mi = 0; mi < 4; ++mi)
        #pragma unroll
        for (int r = 0; r < 4; ++r){
            int m = mb*64 + mi*16 + quad*4 + r;
            hid[(size_t)m*512 + n] = f2bf(fmaxf(acc[mi][r] + bias, 0.f));
        }
}

// out_logits[m][n] = hid(m,:) . emb(n,:) + bcls[n];  M=16384, N=1024(pad of 1000), K=512
__global__ __launch_bounds__(512) void logits_kernel(
    const bf16_t* __restrict__ hid, const bf16_t* __restrict__ emb16,
    const float* __restrict__ bcls, float* __restrict__ out_logits)
{
    const int tid = threadIdx.x, lane = tid & 63, w = tid >> 6, ml = lane & 15, quad = lane >> 4;
    const int nb = blockIdx.x, mb = blockIdx.y;
    const int n = nb*128 + w*16 + ml;
    const bf16_t* brow = emb16 + (size_t)n * 512;
    const bf16_t* rA[4];
    #pragma unroll
    for (int mi = 0; mi < 4; ++mi) rA[mi] = hid + (size_t)(mb*64 + mi*16 + ml) * 512;
    floatx4 acc[4];
    #pragma unroll
    for (int mi = 0; mi < 4; ++mi) acc[mi] = (floatx4){0.f, 0.f, 0.f, 0.f};
    mfma_kloop(rA, brow, 512, quad, acc);
    if (n < V_){
        const float bias = bcls[n];
        #pragma unroll
        for (int mi = 0; mi < 4; ++mi)
            #pragma unroll
            for (int r = 0; r < 4; ++r){
                int m = mb*64 + mi*16 + quad*4 + r;
                out_logits[(size_t)m * V_ + n] = acc[mi][r] + bias;
            }
    }
}

// ---------------------------------------------------------------------------
extern "C" void kernel_launch(void* const* d_in, const int* in_sizes, int n_in,
                              void* d_out, int out_size, void* d_ws, size_t ws_size,
                              hipStream_t stream)
{
    const float* enc  = (const float*)d_in[0];
    const int*   y    = (const int*)  d_in[1];
    const float* Wemb = (const float*)d_in[2];
    const float* Wih1 = (const float*)d_in[3];  const float* bih1 = (const float*)d_in[4];
    const float* Whh1 = (const float*)d_in[5];  const float* bhh1 = (const float*)d_in[6];
    const float* Wih2 = (const float*)d_in[7];  const float* bih2 = (const float*)d_in[8];
    const float* Whh2 = (const float*)d_in[9];  const float* bhh2 = (const float*)d_in[10];
    const float* Wq   = (const float*)d_in[11]; const float* bq   = (const float*)d_in[12];
    const float* Wk   = (const float*)d_in[13]; const float* bk   = (const float*)d_in[14];
    const float* Wv   = (const float*)d_in[15]; const float* bv   = (const float*)d_in[16];
    const float* W1   = (const float*)d_in[17]; const float* b1   = (const float*)d_in[18];
    const float* bcls = (const float*)d_in[19];

    float* outF = (float*)d_out;
    float* out_logits = outF;
    float* out_attn   = outF + (size_t)B_ * T_ * V_;

    // workspace carve (256B aligned). Peak ~96 MB via aliasing:
    //  Region A (33.5MB): enc16 -> k216 -> attn hi/lo
    //  Region B (16.8MB): kq16 -> h2all
    //  Region C (33.5MB): vT   -> hid
    //  out_logits region (65.5MB) doubles as scratch: raw scores [0,33.5) then ctxb [33.5,50.3)
    size_t off = 0;
    char* wsb = (char*)d_ws;
    auto carve = [&](size_t bytes) -> void* {
        void* p = wsb + off;
        off += (bytes + 255) & ~(size_t)255;
        return p;
    };
    bf16_t* enc16 = (bf16_t*)carve((size_t)B_*S_*E_*2);     // Region A
    bf16_t* k216  = enc16;
    bf16_t* attnb = enc16;                                   // 16.8MB
    bf16_t* attnlo= enc16 + (size_t)B_*T_*S_;                // +16.8MB = 33.5MB exact
    bf16_t* kq16  = (bf16_t*)carve((size_t)B_*S_*KQ_*2);    // Region B
    bf16_t* h2all = kq16;                                    // B*T*H*2 = 16.8MB exact
    bf16_t* vT16  = (bf16_t*)carve((size_t)B_*S_*E_*2);     // Region C
    bf16_t* hid   = vT16;                                    // 16.8MB <= 33.5MB
    bf16_t* Wc1   = (bf16_t*)carve((size_t)2048*1024*2);
    bf16_t* Wc2   = (bf16_t*)carve((size_t)2048*1024*2);
    bf16_t* emb16 = (bf16_t*)carve((size_t)1024*512*2);     // padded to 1024 rows
    bf16_t* W116  = (bf16_t*)carve((size_t)512*1024*2);
    bf16_t* WqT16 = (bf16_t*)carve((size_t)512*256*2);
    bf16_t* Wkv16 = (bf16_t*)carve((size_t)768*512*2);
    float*  bcat1 = (float*) carve(2048*4);
    float*  bcat2 = (float*) carve(2048*4);
    float*  bkv   = (float*) carve(768*4);
    float*  kb    = (float*) carve((size_t)B_*S_*4);        // 128 KB
    bf16_t* h1b   = (bf16_t*)carve((size_t)2*B_*H_*2);      // ping-pong
    bf16_t* h2b   = (bf16_t*)carve((size_t)2*B_*H_*2);
    float*  c1    = (float*) carve((size_t)B_*H_*4);
    float*  c2    = (float*) carve((size_t)B_*H_*4);
    unsigned* bar = (unsigned*)carve(256);                   // grid barrier counter

    float*  raw   = out_logits;                              // [16384][512] f32 scratch in out region
    bf16_t* ctxb  = (bf16_t*)((char*)out_logits + (size_t)B_*T_*S_*4);  // next 16.8MB of out region

    // zero recurrent state + barrier counter (ws is poisoned before every call)
    hipMemsetAsync(h1b, 0, (size_t)2*B_*H_*2, stream);
    hipMemsetAsync(h2b, 0, (size_t)2*B_*H_*2, stream);
    hipMemsetAsync(c1,  0, (size_t)B_*H_*4, stream);
    hipMemsetAsync(c2,  0, (size_t)B_*H_*4, stream);
    hipMemsetAsync(bar, 0, 256, stream);

    // setup: convert weights/enc, project k/v (v transposed), fold Wq into k2, bq into kb
    convert_kernel<<<8192, 256, 0, stream>>>(enc, Wemb, Wih1, Whh1, Wih2, Whh2, Wq, Wk, Wv, W1,
                                             bih1, bhh1, bih2, bhh2, bk, bv,
                                             Wc1, Wc2, emb16, W116, WqT16, Wkv16, enc16,
                                             bcat1, bcat2, bkv);
    gemm_kv_kernel<<<dim3(512, 12), 256, 0, stream>>>(enc16, Wkv16, bkv, kq16, vT16);
    gemm_k2_kernel<<<dim3(512, 8), 256, 0, stream>>>(kq16, WqT16, k216);
    kbias_kernel<<<128, 256, 0, stream>>>(kq16, bq, kb);

    // sequential part: ONLY the LSTM chain (64-block cooperative kernel, custom barrier)
    ScanParams sp;
    sp.y = y; sp.emb16 = emb16; sp.Wc1 = Wc1; sp.Wc2 = Wc2;
    sp.bcat1 = bcat1; sp.bcat2 = bcat2;
    sp.h1 = h1b; sp.h2 = h2b; sp.h2all = h2all;
    sp.c1 = c1; sp.c2 = c2; sp.bar = bar;
    void* kargs[] = { (void*)&sp };
    hipLaunchCooperativeKernel((const void*)scan_kernel, dim3(64), dim3(512), kargs, 0, stream);

    // batch-parallel tail: scores -> softmax -> ctx -> hid -> logits
    scores_kernel <<<dim3(8, 4, B_), 256, 0, stream>>>(h2all, k216, kb, raw);
    softmax_kernel<<<(size_t)B_*T_, 512, 0, stream>>>(raw, out_attn, attnb, attnlo);
    ctx_kernel    <<<dim3(8, 4, B_), 256, 0, stream>>>(attnb, attnlo, vT16, ctxb);
    hid_kernel    <<<dim3(4, 256), 512, 0, stream>>>(h2all, ctxb, W116, b1, hid);
    logits_kernel <<<dim3(8, 256), 512, 0, stream>>>(hid, emb16, bcls, out_logits);
}

// Round 5
// 7012.027 us; speedup vs baseline: 2.0020x; 1.0470x over previous
//
#include <hip/hip_runtime.h>
#include <hip/hip_bf16.h>
#include <hip/hip_cooperative_groups.h>
#include <cstdint>
#include <cstddef>

namespace cg = cooperative_groups;

// Problem dims
#define B_   64
#define S_   512
#define T_   256
#define E_   512
#define H_   512
#define KQ_  256
#define V_   1000

typedef unsigned short bf16_t;
typedef __attribute__((ext_vector_type(8))) short short8;   // 8 bf16 (4 VGPRs) — MFMA A/B frag
typedef __attribute__((ext_vector_type(4))) float floatx4;  // MFMA C/D frag

// ---------- small helpers ----------
static __device__ __forceinline__ float bflo(unsigned u){ unsigned x = u << 16;        return __builtin_bit_cast(float, x); }
static __device__ __forceinline__ float bfhi(unsigned u){ unsigned x = u & 0xffff0000u; return __builtin_bit_cast(float, x); }
static __device__ __forceinline__ float bf2f(bf16_t h){ unsigned x = ((unsigned)h) << 16; return __builtin_bit_cast(float, x); }
static __device__ __forceinline__ bf16_t f2bf(float f){
    unsigned u = __builtin_bit_cast(unsigned, f);
    unsigned r = u + 0x7fffu + ((u >> 16) & 1u);   // RNE
    return (bf16_t)(r >> 16);
}
static __device__ __forceinline__ float sigm(float x){ return 1.f / (1.f + __expf(-x)); }
static __device__ __forceinline__ float tanh_(float x){
    float ax = fabsf(x); float t = __expf(-2.f * ax);
    float r = (1.f - t) / (1.f + t);
    return copysignf(r, x);
}
static __device__ __forceinline__ short8 ld8(const bf16_t* p){ return *(const short8*)p; }
static __device__ __forceinline__ floatx4 mfma16(short8 a, short8 b, floatx4 c){
    return __builtin_amdgcn_mfma_f32_16x16x32_bf16(a, b, c, 0, 0, 0);
}

// Shared MFMA K-loop: 4 M-tiles (M=64) x 1 N-tile (N=16) per wave.
// A frag: A[m=lane&15][k=quad*8+j]; B frag from W rows (B^T): B[n=lane&15][k].
// D frag: row(m)=quad*4+r, col(n)=lane&15  (m89-verified convention).
static __device__ __forceinline__ void mfma_kloop(const bf16_t* const rA[4], const bf16_t* rB,
                                                  int K, int quad, floatx4 acc[4]){
    for (int ks = 0; ks < K; ks += 32){
        int ko = ks + quad * 8;
        short8 bf = ld8(rB + ko);
        #pragma unroll
        for (int mi = 0; mi < 4; ++mi)
            acc[mi] = mfma16(ld8(rA[mi] + ko), bf, acc[mi]);
    }
}

// ---------- one-time conversion kernel ----------
// Segments (element index): Wcat1 | Wcat2 | emb(pad 1024 rows) | W1 | WqT | Wkv | enc | bcat1 | bcat2 | bkv
#define CV_E0 2097152UL
#define CV_E1 4194304UL
#define CV_E2 4718592UL
#define CV_E3 5242880UL
#define CV_E4 5373952UL
#define CV_E5 5767168UL
#define CV_E6 22544384UL
#define CV_E7 22546432UL
#define CV_E8 22548480UL
#define CV_E9 22549248UL

__global__ __launch_bounds__(256) void convert_kernel(
    const float* __restrict__ enc,  const float* __restrict__ Wemb,
    const float* __restrict__ Wih1, const float* __restrict__ Whh1,
    const float* __restrict__ Wih2, const float* __restrict__ Whh2,
    const float* __restrict__ Wq,   const float* __restrict__ Wk,
    const float* __restrict__ Wv,   const float* __restrict__ W1,
    const float* __restrict__ bih1, const float* __restrict__ bhh1,
    const float* __restrict__ bih2, const float* __restrict__ bhh2,
    const float* __restrict__ bk,   const float* __restrict__ bv,
    bf16_t* __restrict__ Wc1,  bf16_t* __restrict__ Wc2, bf16_t* __restrict__ emb16,
    bf16_t* __restrict__ W116, bf16_t* __restrict__ WqT16, bf16_t* __restrict__ Wkv16,
    bf16_t* __restrict__ enc16, float* __restrict__ bcat1, float* __restrict__ bcat2,
    float* __restrict__ bkvO)
{
    for (size_t i = (size_t)blockIdx.x * 256 + threadIdx.x; i < CV_E9; i += (size_t)gridDim.x * 256){
        if (i < CV_E0){ size_t r = i >> 10, k = i & 1023;
            float v_ = (k < 512) ? Wih1[r*512 + k] : Whh1[r*512 + (k - 512)];
            Wc1[i] = f2bf(v_);
        } else if (i < CV_E1){ size_t l = i - CV_E0, r = l >> 10, k = l & 1023;
            float v_ = (k < 512) ? Wih2[r*512 + k] : Whh2[r*512 + (k - 512)];
            Wc2[l] = f2bf(v_);
        } else if (i < CV_E2){ size_t l = i - CV_E1, r = l >> 9, k = l & 511;
            emb16[l] = f2bf(r < 1000 ? Wemb[r*512 + k] : 0.f);
        } else if (i < CV_E3){ size_t l = i - CV_E2;
            W116[l] = f2bf(W1[l]);
        } else if (i < CV_E4){ size_t l = i - CV_E3, h = l >> 8, nn = l & 255;
            WqT16[l] = f2bf(Wq[nn*512 + h]);     // WqT[h][d] = Wq[d][h]
        } else if (i < CV_E5){ size_t l = i - CV_E4, r = l >> 9, k = l & 511;
            float v_ = (r < 256) ? Wk[r*512 + k] : Wv[(r - 256)*512 + k];
            Wkv16[l] = f2bf(v_);
        } else if (i < CV_E6){ size_t l = i - CV_E5;
            enc16[l] = f2bf(enc[l]);
        } else if (i < CV_E7){ size_t l = i - CV_E6; bcat1[l] = bih1[l] + bhh1[l]; }
        else if (i < CV_E8){ size_t l = i - CV_E7; bcat2[l] = bih2[l] + bhh2[l]; }
        else { size_t l = i - CV_E8; bkvO[l] = (l < 256) ? bk[l] : bv[l - 256]; }
    }
}

// ---------- k/v projection: [k|v](m,n) = enc(m,:) . Wkv(n,:) + bkv(n);  M=32768, N=768, K=512 ----------
// k output row-major [b*512+s][256]; v output TRANSPOSED per batch: vT[b][e][s] (via LDS tile transpose)
// so the ctx MFMA B-operand (rows indexed by e, contiguous in s) reads coalesced.
__global__ __launch_bounds__(256) void gemm_kv_kernel(
    const bf16_t* __restrict__ enc16, const bf16_t* __restrict__ Wkv16,
    const float* __restrict__ bkv, bf16_t* __restrict__ kq16, bf16_t* __restrict__ vT16)
{
    __shared__ bf16_t tile[64][72];   // 64 m(s) x 64 n(e), pad 72 vs bank conflicts
    const int tid = threadIdx.x, lane = tid & 63, wv = tid >> 6, ml = lane & 15, quad = lane >> 4;
    const int mb = blockIdx.x, nb = blockIdx.y;
    const int n = nb*64 + wv*16 + ml;
    const bf16_t* brow = Wkv16 + (size_t)n * 512;
    const bf16_t* rA[4];
    #pragma unroll
    for (int mi = 0; mi < 4; ++mi) rA[mi] = enc16 + (size_t)(mb*64 + mi*16 + ml) * 512;
    floatx4 acc[4];
    #pragma unroll
    for (int mi = 0; mi < 4; ++mi) acc[mi] = (floatx4){0.f, 0.f, 0.f, 0.f};
    mfma_kloop(rA, brow, 512, quad, acc);
    const float bias = bkv[n];
    if (nb < 4){
        #pragma unroll
        for (int mi = 0; mi < 4; ++mi)
            #pragma unroll
            for (int r = 0; r < 4; ++r){
                int m = mb*64 + mi*16 + quad*4 + r;
                kq16[(size_t)m*256 + n] = f2bf(acc[mi][r] + bias);
            }
    } else {
        #pragma unroll
        for (int mi = 0; mi < 4; ++mi)
            #pragma unroll
            for (int r = 0; r < 4; ++r)
                tile[mi*16 + quad*4 + r][wv*16 + ml] = f2bf(acc[mi][r] + bias);
        __syncthreads();
        const int b = mb >> 3, s0 = (mb & 7) * 64, e0 = nb*64 - 256;
        const int eloc = tid >> 2, sc = (tid & 3) * 16;
        bf16_t* dst = vT16 + ((size_t)(b*512 + e0 + eloc)) * 512 + s0 + sc;
        #pragma unroll
        for (int j = 0; j < 16; ++j) dst[j] = tile[sc + j][eloc];
    }
}

// ---------- k2 = k @ Wq: M=32768, N=512, K=256 ----------
__global__ __launch_bounds__(256) void gemm_k2_kernel(
    const bf16_t* __restrict__ kq16, const bf16_t* __restrict__ WqT16, bf16_t* __restrict__ k216)
{
    const int tid = threadIdx.x, lane = tid & 63, wv = tid >> 6, ml = lane & 15, quad = lane >> 4;
    const int mb = blockIdx.x, nb = blockIdx.y;
    const int n = nb*64 + wv*16 + ml;
    const bf16_t* brow = WqT16 + (size_t)n * 256;
    const bf16_t* rA[4];
    #pragma unroll
    for (int mi = 0; mi < 4; ++mi) rA[mi] = kq16 + (size_t)(mb*64 + mi*16 + ml) * 256;
    floatx4 acc[4];
    #pragma unroll
    for (int mi = 0; mi < 4; ++mi) acc[mi] = (floatx4){0.f, 0.f, 0.f, 0.f};
    mfma_kloop(rA, brow, 256, quad, acc);
    #pragma unroll
    for (int mi = 0; mi < 4; ++mi)
        #pragma unroll
        for (int r = 0; r < 4; ++r){
            int m = mb*64 + mi*16 + quad*4 + r;
            k216[(size_t)m*512 + n] = f2bf(acc[mi][r]);
        }
}

// ---------- kb[m] = k[m,:] . bq ----------
__global__ __launch_bounds__(256) void kbias_kernel(
    const bf16_t* __restrict__ kq16, const float* __restrict__ bq, float* __restrict__ kb)
{
    int m = blockIdx.x * 256 + threadIdx.x;  // 32768 total
    const unsigned* row = (const unsigned*)(kq16 + (size_t)m * 256);
    float acc = 0.f;
    #pragma unroll 8
    for (int i = 0; i < 128; ++i){
        unsigned u = row[i];
        acc += bflo(u) * bq[2*i] + bfhi(u) * bq[2*i + 1];
    }
    kb[m] = acc;
}

// ---------- LSTM cell, 8-wave variant: waves (gate g, K-half kh). K-half 0 = x@Wih, 1 = h@Whh ----------
// smemf layout: [8 waves][64 rows][17] floats (pad 17 breaks bank conflicts)
#define LG(w_, b_, j_) smemf[((w_)*64 + (b_))*17 + (j_)]
static __device__ __forceinline__ void lstm_part2(
    int tid, int jblk,
    const bf16_t* __restrict__ xrows, const bf16_t* __restrict__ emb,
    const int* __restrict__ y, int tok_col, int use_emb,
    const bf16_t* __restrict__ h_in, bf16_t* __restrict__ h_out,
    float* __restrict__ c_st, const bf16_t* __restrict__ Wcat,
    const float* __restrict__ bcat, bf16_t* __restrict__ arch,  // arch: h2all + t*512, row stride T_*512
    float* smemf)
{
    const int lane = tid & 63, w = tid >> 6, ml = lane & 15, quad = lane >> 4;
    const int g = w & 3, kh = w >> 2;
    const int j0 = jblk * 16;
    const bf16_t* brow = Wcat + (size_t)(g*512 + j0 + ml) * 1024 + (size_t)kh * 512;
    const bf16_t* rA[4];
    #pragma unroll
    for (int mi = 0; mi < 4; ++mi){
        int b = mi*16 + ml;
        if (kh == 0){
            if (use_emb){
                int tok = (tok_col < 0) ? 0 : y[b * T_ + tok_col];   // SOS=0
                rA[mi] = emb + (size_t)tok * 512;
            } else rA[mi] = xrows + (size_t)b * 512;
        } else {
            rA[mi] = h_in + (size_t)b * 512;
        }
    }
    floatx4 acc[4];
    #pragma unroll
    for (int mi = 0; mi < 4; ++mi) acc[mi] = (floatx4){0.f, 0.f, 0.f, 0.f};
    for (int ks = 0; ks < 512; ks += 32){
        int ko = ks + quad * 8;
        short8 bf = ld8(brow + ko);
        #pragma unroll
        for (int mi = 0; mi < 4; ++mi) acc[mi] = mfma16(ld8(rA[mi] + ko), bf, acc[mi]);
    }
    #pragma unroll
    for (int mi = 0; mi < 4; ++mi)
        #pragma unroll
        for (int r = 0; r < 4; ++r)
            LG(w, mi*16 + quad*4 + r, ml) = acc[mi][r];
    __syncthreads();
    // cell update: 512 threads x 2 cells (64 b x 16 j)
    const int jj = tid & 15, b0 = tid >> 4;  // b0 in [0,32)
    const int j = j0 + jj;
    const float bi = bcat[j], bff = bcat[512 + j], bg = bcat[1024 + j], bo = bcat[1536 + j];
    #pragma unroll
    for (int c = 0; c < 2; ++c){
        int b = b0 + 32 * c;
        float gi = LG(0, b, jj) + LG(4, b, jj) + bi;
        float gf = LG(1, b, jj) + LG(5, b, jj) + bff;
        float gg = LG(2, b, jj) + LG(6, b, jj) + bg;
        float go = LG(3, b, jj) + LG(7, b, jj) + bo;
        size_t idx = (size_t)b * 512 + j;
        float cn = sigm(gf) * c_st[idx] + sigm(gi) * tanh_(gg);
        float hn = sigm(go) * tanh_(cn);
        c_st[idx] = cn;
        bf16_t hb = f2bf(hn);
        h_out[idx] = hb;
        if (arch) arch[(size_t)b * ((size_t)T_ * 512) + j] = hb;  // h2all[b*T+t][j]
    }
}

// ---------- cooperative scan: ONLY the recurrent LSTM chain (attention never feeds back) ----------
// Period p: LSTM1(t=p) on blocks 0..31 | LSTM2(t=p-1) on blocks 32..63 (archives h2(t) to h2all).
// Grid = 64 blocks.
// Grid barrier v4: DISTRIBUTED per-block flags, arrival via UNCONTENDED fetch_add.
// Round-2 postmortem: 64 device-scope RMWs on ONE cacheline serialize at the cross-XCD
// coherence point (~20 us). v3 used plain atomic release-stores to 64 distinct lines; the
// only untested instruction class (possible cross-XCD visibility hazard -> hang). v4 keeps
// the distributed topology but arrives with fetch_add(1, RELEASE, AGENT) on the block's OWN
// flag — the exact instruction proven cross-XCD-visible in round 2, now contention-free so
// the 64 RMWs pipeline in parallel. Poll: 64-lane gather of relaxed agent loads (proven in
// round 2). Acquire: __threadfence + __syncthreads (proven in round 2).
struct ScanParams {
    const int* y;
    const bf16_t *emb16, *Wc1, *Wc2;
    const float *bcat1, *bcat2;
    bf16_t *h1, *h2, *h2all;
    float *c1, *c2;
    unsigned* bar;    // 64 flags, 32-uint (128B) stride
};

#define SPER (T_ + 1)   // 257 periods
#define NBLK 64
#define FSTRIDE 32      // uints between flags (128B)

__global__ __launch_bounds__(512, 2) void scan_kernel(ScanParams P)
{
    __shared__ __align__(16) float smemf[8704];
    const int bx = blockIdx.x, tid = threadIdx.x;
    const size_t BH = (size_t)B_ * H_;

    for (int p = 0; p < SPER; ++p){
        if (bx < 32){
            int t = p;
            if (t < T_){
                lstm_part2(tid, bx, nullptr, P.emb16, P.y, t - 1, 1,
                           P.h1 + ((t - 1) & 1) * BH, P.h1 + (t & 1) * BH,
                           P.c1, P.Wc1, P.bcat1, nullptr, smemf);
            }
        } else {
            int t = p - 1;
            if (t >= 0){
                lstm_part2(tid, bx - 32, P.h1 + (t & 1) * BH, nullptr, nullptr, 0, 0,
                           P.h2 + ((t - 1) & 1) * BH, P.h2 + (t & 1) * BH,
                           P.c2, P.Wc2, P.bcat2, P.h2all + (size_t)t * 512, smemf);
            }
        }
        // ---- distributed-flag grid barrier ----
        __syncthreads();   // block stores drained (compiler emits vmcnt(0) before s_barrier)
        if (tid < NBLK){
            if (tid == 0)
                __hip_atomic_fetch_add(&P.bar[(size_t)bx * FSTRIDE], 1u,
                                       __ATOMIC_RELEASE, __HIP_MEMORY_SCOPE_AGENT);
            // lane i polls block i's flag; wave proceeds when every lane's flag reached p+1
            while (__hip_atomic_load(&P.bar[(size_t)tid * FSTRIDE],
                                     __ATOMIC_RELAXED, __HIP_MEMORY_SCOPE_AGENT)
                   < (unsigned)(p + 1))
                __builtin_amdgcn_s_sleep(1);
            __threadfence();   // acquire: invalidate stale L1/L2 before next period's reads
        }
        __syncthreads();
    }
}

// ---------- batched post-scan stages (fully parallel over all 16384 (b,t) rows) ----------

// raw[b*T+t][s] = (h2all[b*T+t] . k2[b][s] + kb[b][s]) / 16;  per batch: M=256, N=512, K=512
__global__ __launch_bounds__(256) void scores_kernel(
    const bf16_t* __restrict__ h2all, const bf16_t* __restrict__ k216,
    const float* __restrict__ kb, float* __restrict__ raw)
{
    const int tid = threadIdx.x, lane = tid & 63, wv = tid >> 6, ml = lane & 15, quad = lane >> 4;
    const int nt = blockIdx.x, mt = blockIdx.y, b = blockIdx.z;
    const int n = nt*64 + wv*16 + ml;            // s
    const bf16_t* brow = k216 + ((size_t)b*512 + n) * 512;
    const bf16_t* rA[4];
    #pragma unroll
    for (int mi = 0; mi < 4; ++mi)
        rA[mi] = h2all + ((size_t)b*T_ + mt*64 + mi*16 + ml) * 512;
    floatx4 acc[4];
    #pragma unroll
    for (int mi = 0; mi < 4; ++mi) acc[mi] = (floatx4){0.f, 0.f, 0.f, 0.f};
    mfma_kloop(rA, brow, 512, quad, acc);
    const float kbn = kb[(size_t)b*512 + n];
    #pragma unroll
    for (int mi = 0; mi < 4; ++mi)
        #pragma unroll
        for (int r = 0; r < 4; ++r){
            int m = mt*64 + mi*16 + quad*4 + r;  // t
            raw[((size_t)b*T_ + m)*512 + n] = (acc[mi][r] + kbn) * 0.0625f;
        }
}

// softmax over s for each of the 16384 rows; writes out_attn (f32) and attn split hi/lo bf16
// (hi+lo two-term split keeps ctx accumulation at f32-attn accuracy through the bf16 MFMA).
__global__ __launch_bounds__(512) void softmax_kernel(
    const float* __restrict__ raw, float* __restrict__ out_attn,
    bf16_t* __restrict__ attnb, bf16_t* __restrict__ attnlo)
{
    __shared__ float red[16];
    const int tid = threadIdx.x;
    const size_t r = blockIdx.x;
    float sc = raw[r*512 + tid];
    float mx = sc;
    #pragma unroll
    for (int o = 32; o > 0; o >>= 1) mx = fmaxf(mx, __shfl_xor(mx, o, 64));
    if ((tid & 63) == 0) red[tid >> 6] = mx;
    __syncthreads();
    float gmax = red[0];
    #pragma unroll
    for (int i = 1; i < 8; ++i) gmax = fmaxf(gmax, red[i]);
    float e = __expf(sc - gmax);
    float sm = e;
    #pragma unroll
    for (int o = 32; o > 0; o >>= 1) sm += __shfl_xor(sm, o, 64);
    if ((tid & 63) == 0) red[8 + (tid >> 6)] = sm;
    __syncthreads();
    float tot = red[8];
    #pragma unroll
    for (int i = 1; i < 8; ++i) tot += red[8 + i];
    float attn = e / tot;
    out_attn[r*512 + tid] = attn;
    bf16_t hi = f2bf(attn);
    attnb [r*512 + tid] = hi;
    attnlo[r*512 + tid] = f2bf(attn - bf2f(hi));
}

// ctx[b*T+t][e] = sum_s attn[b,t,s] * v[b,s,e];  A = attn hi/lo rows, B-rows = vT[b][e][:]
__global__ __launch_bounds__(256) void ctx_kernel(
    const bf16_t* __restrict__ attnb, const bf16_t* __restrict__ attnlo,
    const bf16_t* __restrict__ vT16, bf16_t* __restrict__ ctxb)
{
    const int tid = threadIdx.x, lane = tid & 63, wv = tid >> 6, ml = lane & 15, quad = lane >> 4;
    const int nt = blockIdx.x, mt = blockIdx.y, b = blockIdx.z;
    const int n = nt*64 + wv*16 + ml;            // e
    const bf16_t* brow = vT16 + ((size_t)b*512 + n) * 512;
    const bf16_t* rA[4]; const bf16_t* rAlo[4];
    #pragma unroll
    for (int mi = 0; mi < 4; ++mi){
        size_t row = (size_t)b*T_ + mt*64 + mi*16 + ml;
        rA[mi]   = attnb  + row * 512;
        rAlo[mi] = attnlo + row * 512;
    }
    floatx4 acc[4];
    #pragma unroll
    for (int mi = 0; mi < 4; ++mi) acc[mi] = (floatx4){0.f, 0.f, 0.f, 0.f};
    mfma_kloop(rA,   brow, 512, quad, acc);
    mfma_kloop(rAlo, brow, 512, quad, acc);
    #pragma unroll
    for (int mi = 0; mi < 4; ++mi)
        #pragma unroll
        for (int r = 0; r < 4; ++r){
            int m = mt*64 + mi*16 + quad*4 + r;  // t
            ctxb[((size_t)b*T_ + m)*512 + n] = f2bf(acc[mi][r]);
        }
}

// hid[m][n] = relu([h2all|ctx](m,:) . W1row(n,:) + b1[n]);  M=16384, N=512, K=1024 (two halves)
__global__ __launch_bounds__(512) void hid_kernel(
    const bf16_t* __restrict__ h2all, const bf16_t* __restrict__ ctxb,
    const bf16_t* __restrict__ W116, const float* __restrict__ b1, bf16_t* __restrict__ hid)
{
    const int tid = threadIdx.x, lane = tid & 63, w = tid >> 6, ml = lane & 15, quad = lane >> 4;
    const int nb = blockIdx.x, mb = blockIdx.y;
    const int n = nb*128 + w*16 + ml;
    const bf16_t* brow = W116 + (size_t)n * 1024;
    const bf16_t* rA[4]; const bf16_t* rC[4];
    #pragma unroll
    for (int mi = 0; mi < 4; ++mi){
        size_t m = (size_t)(mb*64 + mi*16 + ml);
        rA[mi] = h2all + m * 512;
        rC[mi] = ctxb  + m * 512;
    }
    floatx4 acc[4];
    #pragma unroll
    for (int mi = 0; mi < 4; ++mi) acc[mi] = (floatx4){0.f, 0.f, 0.f, 0.f};
    mfma_kloop(rA, brow,       512, quad, acc);
    mfma_kloop(rC, brow + 512, 512, quad, acc);
    const float bias = b1[n];
    #pragma unroll
    for (int mi = 0; mi < 4; ++mi)
        #pragma unroll
        for (int r = 0; r < 4; ++r){
            int m = mb*64 + mi*16 + quad*4 + r;
            hid[(size_t)m*512 + n] = f2bf(fmaxf(acc[mi][r] + bias, 0.f));
        }
}

// out_logits[m][n] = hid(m,:) . emb(n,:) + bcls[n];  M=16384, N=1024(pad of 1000), K=512
__global__ __launch_bounds__(512) void logits_kernel(
    const bf16_t* __restrict__ hid, const bf16_t* __restrict__ emb16,
    const float* __restrict__ bcls, float* __restrict__ out_logits)
{
    const int tid = threadIdx.x, lane = tid & 63, w = tid >> 6, ml = lane & 15, quad = lane >> 4;
    const int nb = blockIdx.x, mb = blockIdx.y;
    const int n = nb*128 + w*16 + ml;
    const bf16_t* brow = emb16 + (size_t)n * 512;
    const bf16_t* rA[4];
    #pragma unroll
    for (int mi = 0; mi < 4; ++mi) rA[mi] = hid + (size_t)(mb*64 + mi*16 + ml) * 512;
    floatx4 acc[4];
    #pragma unroll
    for (int mi = 0; mi < 4; ++mi) acc[mi] = (floatx4){0.f, 0.f, 0.f, 0.f};
    mfma_kloop(rA, brow, 512, quad, acc);
    if (n < V_){
        const float bias = bcls[n];
        #pragma unroll
        for (int mi = 0; mi < 4; ++mi)
            #pragma unroll
            for (int r = 0; r < 4; ++r){
                int m = mb*64 + mi*16 + quad*4 + r;
                out_logits[(size_t)m * V_ + n] = acc[mi][r] + bias;
            }
    }
}

// ---------------------------------------------------------------------------
extern "C" void kernel_launch(void* const* d_in, const int* in_sizes, int n_in,
                              void* d_out, int out_size, void* d_ws, size_t ws_size,
                              hipStream_t stream)
{
    const float* enc  = (const float*)d_in[0];
    const int*   y    = (const int*)  d_in[1];
    const float* Wemb = (const float*)d_in[2];
    const float* Wih1 = (const float*)d_in[3];  const float* bih1 = (const float*)d_in[4];
    const float* Whh1 = (const float*)d_in[5];  const float* bhh1 = (const float*)d_in[6];
    const float* Wih2 = (const float*)d_in[7];  const float* bih2 = (const float*)d_in[8];
    const float* Whh2 = (const float*)d_in[9];  const float* bhh2 = (const float*)d_in[10];
    const float* Wq   = (const float*)d_in[11]; const float* bq   = (const float*)d_in[12];
    const float* Wk   = (const float*)d_in[13]; const float* bk   = (const float*)d_in[14];
    const float* Wv   = (const float*)d_in[15]; const float* bv   = (const float*)d_in[16];
    const float* W1   = (const float*)d_in[17]; const float* b1   = (const float*)d_in[18];
    const float* bcls = (const float*)d_in[19];

    float* outF = (float*)d_out;
    float* out_logits = outF;
    float* out_attn   = outF + (size_t)B_ * T_ * V_;

    // workspace carve (256B aligned). Peak ~96 MB via aliasing:
    //  Region A (33.5MB): enc16 -> k216 -> attn hi/lo
    //  Region B (16.8MB): kq16 -> h2all
    //  Region C (33.5MB): vT   -> hid
    //  out_logits region (65.5MB) doubles as scratch: raw scores [0,33.5) then ctxb [33.5,50.3)
    size_t off = 0;
    char* wsb = (char*)d_ws;
    auto carve = [&](size_t bytes) -> void* {
        void* p = wsb + off;
        off += (bytes + 255) & ~(size_t)255;
        return p;
    };
    bf16_t* enc16 = (bf16_t*)carve((size_t)B_*S_*E_*2);     // Region A
    bf16_t* k216  = enc16;
    bf16_t* attnb = enc16;                                   // 16.8MB
    bf16_t* attnlo= enc16 + (size_t)B_*T_*S_;                // +16.8MB = 33.5MB exact
    bf16_t* kq16  = (bf16_t*)carve((size_t)B_*S_*KQ_*2);    // Region B
    bf16_t* h2all = kq16;                                    // B*T*H*2 = 16.8MB exact
    bf16_t* vT16  = (bf16_t*)carve((size_t)B_*S_*E_*2);     // Region C
    bf16_t* hid   = vT16;                                    // 16.8MB <= 33.5MB
    bf16_t* Wc1   = (bf16_t*)carve((size_t)2048*1024*2);
    bf16_t* Wc2   = (bf16_t*)carve((size_t)2048*1024*2);
    bf16_t* emb16 = (bf16_t*)carve((size_t)1024*512*2);     // padded to 1024 rows
    bf16_t* W116  = (bf16_t*)carve((size_t)512*1024*2);
    bf16_t* WqT16 = (bf16_t*)carve((size_t)512*256*2);
    bf16_t* Wkv16 = (bf16_t*)carve((size_t)768*512*2);
    float*  bcat1 = (float*) carve(2048*4);
    float*  bcat2 = (float*) carve(2048*4);
    float*  bkv   = (float*) carve(768*4);
    float*  kb    = (float*) carve((size_t)B_*S_*4);        // 128 KB
    bf16_t* h1b   = (bf16_t*)carve((size_t)2*B_*H_*2);      // ping-pong
    bf16_t* h2b   = (bf16_t*)carve((size_t)2*B_*H_*2);
    float*  c1    = (float*) carve((size_t)B_*H_*4);
    float*  c2    = (float*) carve((size_t)B_*H_*4);
    unsigned* bar = (unsigned*)carve(NBLK * FSTRIDE * 4);    // 64 distributed flags, 128B apart

    float*  raw   = out_logits;                              // [16384][512] f32 scratch in out region
    bf16_t* ctxb  = (bf16_t*)((char*)out_logits + (size_t)B_*T_*S_*4);  // next 16.8MB of out region

    // zero recurrent state + barrier flags (ws is poisoned before every call)
    hipMemsetAsync(h1b, 0, (size_t)2*B_*H_*2, stream);
    hipMemsetAsync(h2b, 0, (size_t)2*B_*H_*2, stream);
    hipMemsetAsync(c1,  0, (size_t)B_*H_*4, stream);
    hipMemsetAsync(c2,  0, (size_t)B_*H_*4, stream);
    hipMemsetAsync(bar, 0, NBLK * FSTRIDE * 4, stream);

    // setup: convert weights/enc, project k/v (v transposed), fold Wq into k2, bq into kb
    convert_kernel<<<8192, 256, 0, stream>>>(enc, Wemb, Wih1, Whh1, Wih2, Whh2, Wq, Wk, Wv, W1,
                                             bih1, bhh1, bih2, bhh2, bk, bv,
                                             Wc1, Wc2, emb16, W116, WqT16, Wkv16, enc16,
                                             bcat1, bcat2, bkv);
    gemm_kv_kernel<<<dim3(512, 12), 256, 0, stream>>>(enc16, Wkv16, bkv, kq16, vT16);
    gemm_k2_kernel<<<dim3(512, 8), 256, 0, stream>>>(kq16, WqT16, k216);
    kbias_kernel<<<128, 256, 0, stream>>>(kq16, bq, kb);

    // sequential part: ONLY the LSTM chain (64-block cooperative kernel, distributed-flag barrier)
    ScanParams sp;
    sp.y = y; sp.emb16 = emb16; sp.Wc1 = Wc1; sp.Wc2 = Wc2;
    sp.bcat1 = bcat1; sp.bcat2 = bcat2;
    sp.h1 = h1b; sp.h2 = h2b; sp.h2all = h2all;
    sp.c1 = c1; sp.c2 = c2; sp.bar = bar;
    void* kargs[] = { (void*)&sp };
    hipLaunchCooperativeKernel((const void*)scan_kernel, dim3(64), dim3(512), kargs, 0, stream);

    // batch-parallel tail: scores -> softmax -> ctx -> hid -> logits
    scores_kernel <<<dim3(8, 4, B_), 256, 0, stream>>>(h2all, k216, kb, raw);
    softmax_kernel<<<(size_t)B_*T_, 512, 0, stream>>>(raw, out_attn, attnb, attnlo);
    ctx_kernel    <<<dim3(8, 4, B_), 256, 0, stream>>>(attnb, attnlo, vT16, ctxb);
    hid_kernel    <<<dim3(4, 256), 512, 0, stream>>>(h2all, ctxb, W116, b1, hid);
    logits_kernel <<<dim3(8, 256), 512, 0, stream>>>(hid, emb16, bcls, out_logits);
}

// Round 6
// 5937.414 us; speedup vs baseline: 2.3644x; 1.1810x over previous
//
#include <hip/hip_runtime.h>
#include <hip/hip_bf16.h>
#include <hip/hip_cooperative_groups.h>
#include <cstdint>
#include <cstddef>

namespace cg = cooperative_groups;

// Problem dims
#define B_   64
#define S_   512
#define T_   256
#define E_   512
#define H_   512
#define KQ_  256
#define V_   1000

typedef unsigned short bf16_t;
typedef __attribute__((ext_vector_type(8))) short short8;   // 8 bf16 (4 VGPRs) — MFMA A/B frag
typedef __attribute__((ext_vector_type(4))) float floatx4;  // MFMA C/D frag

// ---------- small helpers ----------
static __device__ __forceinline__ float bflo(unsigned u){ unsigned x = u << 16;        return __builtin_bit_cast(float, x); }
static __device__ __forceinline__ float bfhi(unsigned u){ unsigned x = u & 0xffff0000u; return __builtin_bit_cast(float, x); }
static __device__ __forceinline__ float bf2f(bf16_t h){ unsigned x = ((unsigned)h) << 16; return __builtin_bit_cast(float, x); }
static __device__ __forceinline__ bf16_t f2bf(float f){
    unsigned u = __builtin_bit_cast(unsigned, f);
    unsigned r = u + 0x7fffu + ((u >> 16) & 1u);   // RNE
    return (bf16_t)(r >> 16);
}
static __device__ __forceinline__ float sigm(float x){ return 1.f / (1.f + __expf(-x)); }
static __device__ __forceinline__ float tanh_(float x){
    float ax = fabsf(x); float t = __expf(-2.f * ax);
    float r = (1.f - t) / (1.f + t);
    return copysignf(r, x);
}
static __device__ __forceinline__ short8 ld8(const bf16_t* p){ return *(const short8*)p; }
static __device__ __forceinline__ floatx4 mfma16(short8 a, short8 b, floatx4 c){
    return __builtin_amdgcn_mfma_f32_16x16x32_bf16(a, b, c, 0, 0, 0);
}

// Shared MFMA K-loop: 4 M-tiles (M=64) x 1 N-tile (N=16) per wave.
// A frag: A[m=lane&15][k=quad*8+j]; B frag from W rows (B^T): B[n=lane&15][k].
// D frag: row(m)=quad*4+r, col(n)=lane&15  (m89-verified convention).
static __device__ __forceinline__ void mfma_kloop(const bf16_t* const rA[4], const bf16_t* rB,
                                                  int K, int quad, floatx4 acc[4]){
    for (int ks = 0; ks < K; ks += 32){
        int ko = ks + quad * 8;
        short8 bf = ld8(rB + ko);
        #pragma unroll
        for (int mi = 0; mi < 4; ++mi)
            acc[mi] = mfma16(ld8(rA[mi] + ko), bf, acc[mi]);
    }
}

// ---------- one-time conversion kernel ----------
// Segments (element index): Wcat1 | Wcat2 | emb(pad 1024 rows) | W1 | WqT | Wkv | enc | bcat1 | bcat2 | bkv
#define CV_E0 2097152UL
#define CV_E1 4194304UL
#define CV_E2 4718592UL
#define CV_E3 5242880UL
#define CV_E4 5373952UL
#define CV_E5 5767168UL
#define CV_E6 22544384UL
#define CV_E7 22546432UL
#define CV_E8 22548480UL
#define CV_E9 22549248UL

__global__ __launch_bounds__(256) void convert_kernel(
    const float* __restrict__ enc,  const float* __restrict__ Wemb,
    const float* __restrict__ Wih1, const float* __restrict__ Whh1,
    const float* __restrict__ Wih2, const float* __restrict__ Whh2,
    const float* __restrict__ Wq,   const float* __restrict__ Wk,
    const float* __restrict__ Wv,   const float* __restrict__ W1,
    const float* __restrict__ bih1, const float* __restrict__ bhh1,
    const float* __restrict__ bih2, const float* __restrict__ bhh2,
    const float* __restrict__ bk,   const float* __restrict__ bv,
    bf16_t* __restrict__ Wc1,  bf16_t* __restrict__ Wc2, bf16_t* __restrict__ emb16,
    bf16_t* __restrict__ W116, bf16_t* __restrict__ WqT16, bf16_t* __restrict__ Wkv16,
    bf16_t* __restrict__ enc16, float* __restrict__ bcat1, float* __restrict__ bcat2,
    float* __restrict__ bkvO)
{
    for (size_t i = (size_t)blockIdx.x * 256 + threadIdx.x; i < CV_E9; i += (size_t)gridDim.x * 256){
        if (i < CV_E0){ size_t r = i >> 10, k = i & 1023;
            float v_ = (k < 512) ? Wih1[r*512 + k] : Whh1[r*512 + (k - 512)];
            Wc1[i] = f2bf(v_);
        } else if (i < CV_E1){ size_t l = i - CV_E0, r = l >> 10, k = l & 1023;
            float v_ = (k < 512) ? Wih2[r*512 + k] : Whh2[r*512 + (k - 512)];
            Wc2[l] = f2bf(v_);
        } else if (i < CV_E2){ size_t l = i - CV_E1, r = l >> 9, k = l & 511;
            emb16[l] = f2bf(r < 1000 ? Wemb[r*512 + k] : 0.f);
        } else if (i < CV_E3){ size_t l = i - CV_E2;
            W116[l] = f2bf(W1[l]);
        } else if (i < CV_E4){ size_t l = i - CV_E3, h = l >> 8, nn = l & 255;
            WqT16[l] = f2bf(Wq[nn*512 + h]);     // WqT[h][d] = Wq[d][h]
        } else if (i < CV_E5){ size_t l = i - CV_E4, r = l >> 9, k = l & 511;
            float v_ = (r < 256) ? Wk[r*512 + k] : Wv[(r - 256)*512 + k];
            Wkv16[l] = f2bf(v_);
        } else if (i < CV_E6){ size_t l = i - CV_E5;
            enc16[l] = f2bf(enc[l]);
        } else if (i < CV_E7){ size_t l = i - CV_E6; bcat1[l] = bih1[l] + bhh1[l]; }
        else if (i < CV_E8){ size_t l = i - CV_E7; bcat2[l] = bih2[l] + bhh2[l]; }
        else { size_t l = i - CV_E8; bkvO[l] = (l < 256) ? bk[l] : bv[l - 256]; }
    }
}

// ---------- k/v projection: [k|v](m,n) = enc(m,:) . Wkv(n,:) + bkv(n);  M=32768, N=768, K=512 ----------
// k output row-major [b*512+s][256]; v output TRANSPOSED per batch: vT[b][e][s] (via LDS tile transpose)
// so the ctx MFMA B-operand (rows indexed by e, contiguous in s) reads coalesced.
__global__ __launch_bounds__(256) void gemm_kv_kernel(
    const bf16_t* __restrict__ enc16, const bf16_t* __restrict__ Wkv16,
    const float* __restrict__ bkv, bf16_t* __restrict__ kq16, bf16_t* __restrict__ vT16)
{
    __shared__ bf16_t tile[64][72];   // 64 m(s) x 64 n(e), pad 72 vs bank conflicts
    const int tid = threadIdx.x, lane = tid & 63, wv = tid >> 6, ml = lane & 15, quad = lane >> 4;
    const int mb = blockIdx.x, nb = blockIdx.y;
    const int n = nb*64 + wv*16 + ml;
    const bf16_t* brow = Wkv16 + (size_t)n * 512;
    const bf16_t* rA[4];
    #pragma unroll
    for (int mi = 0; mi < 4; ++mi) rA[mi] = enc16 + (size_t)(mb*64 + mi*16 + ml) * 512;
    floatx4 acc[4];
    #pragma unroll
    for (int mi = 0; mi < 4; ++mi) acc[mi] = (floatx4){0.f, 0.f, 0.f, 0.f};
    mfma_kloop(rA, brow, 512, quad, acc);
    const float bias = bkv[n];
    if (nb < 4){
        #pragma unroll
        for (int mi = 0; mi < 4; ++mi)
            #pragma unroll
            for (int r = 0; r < 4; ++r){
                int m = mb*64 + mi*16 + quad*4 + r;
                kq16[(size_t)m*256 + n] = f2bf(acc[mi][r] + bias);
            }
    } else {
        #pragma unroll
        for (int mi = 0; mi < 4; ++mi)
            #pragma unroll
            for (int r = 0; r < 4; ++r)
                tile[mi*16 + quad*4 + r][wv*16 + ml] = f2bf(acc[mi][r] + bias);
        __syncthreads();
        const int b = mb >> 3, s0 = (mb & 7) * 64, e0 = nb*64 - 256;
        const int eloc = tid >> 2, sc = (tid & 3) * 16;
        bf16_t* dst = vT16 + ((size_t)(b*512 + e0 + eloc)) * 512 + s0 + sc;
        #pragma unroll
        for (int j = 0; j < 16; ++j) dst[j] = tile[sc + j][eloc];
    }
}

// ---------- k2 = k @ Wq: M=32768, N=512, K=256 ----------
__global__ __launch_bounds__(256) void gemm_k2_kernel(
    const bf16_t* __restrict__ kq16, const bf16_t* __restrict__ WqT16, bf16_t* __restrict__ k216)
{
    const int tid = threadIdx.x, lane = tid & 63, wv = tid >> 6, ml = lane & 15, quad = lane >> 4;
    const int mb = blockIdx.x, nb = blockIdx.y;
    const int n = nb*64 + wv*16 + ml;
    const bf16_t* brow = WqT16 + (size_t)n * 256;
    const bf16_t* rA[4];
    #pragma unroll
    for (int mi = 0; mi < 4; ++mi) rA[mi] = kq16 + (size_t)(mb*64 + mi*16 + ml) * 256;
    floatx4 acc[4];
    #pragma unroll
    for (int mi = 0; mi < 4; ++mi) acc[mi] = (floatx4){0.f, 0.f, 0.f, 0.f};
    mfma_kloop(rA, brow, 256, quad, acc);
    #pragma unroll
    for (int mi = 0; mi < 4; ++mi)
        #pragma unroll
        for (int r = 0; r < 4; ++r){
            int m = mb*64 + mi*16 + quad*4 + r;
            k216[(size_t)m*512 + n] = f2bf(acc[mi][r]);
        }
}

// ---------- kb[m] = k[m,:] . bq ----------
__global__ __launch_bounds__(256) void kbias_kernel(
    const bf16_t* __restrict__ kq16, const float* __restrict__ bq, float* __restrict__ kb)
{
    int m = blockIdx.x * 256 + threadIdx.x;  // 32768 total
    const unsigned* row = (const unsigned*)(kq16 + (size_t)m * 256);
    float acc = 0.f;
    #pragma unroll 8
    for (int i = 0; i < 128; ++i){
        unsigned u = row[i];
        acc += bflo(u) * bq[2*i] + bfhi(u) * bq[2*i + 1];
    }
    kb[m] = acc;
}

// ---------- cooperative scan: ONLY the recurrent LSTM chain (attention never feeds back) ----------
// Period p: LSTM1(t=p) on blocks 0..31 | LSTM2(t=p-1) on blocks 32..63 (archives h2(t) to h2all).
// Grid = 64 blocks; distributed-flag barrier (round-5-proven).
//
// Round-5 postmortem: period stuck at ~23 us although barrier protocol changes only moved
// ~1-4 us. Diagnosis: the per-period __threadfence() acquire invalidates the XCD's L1+L2
// (non-coherent across XCDs), discarding each block's 128 KB weight slice -> re-fetched
// from Infinity Cache at LLC latency EVERY period (~15-18 us, invisible in FETCH_SIZE
// since LLC hits aren't HBM fetches). Round-6 lever: make loop-invariant state fence-proof
// by holding it in REGISTERS across the scan:
//   - weight B-fragments: 16 x short8 = 64 VGPRs/lane (statically indexed, fully unrolled)
//   - gate biases: 4 floats/thread
//   - c-state: 2 floats/thread (same thread owns same (b,j) every period) -> no c traffic
// Per-period memory traffic is then just h_in (cross-block, genuinely coherent) + emb rows.
// smemf layout: [8 waves][64 rows][17] floats (pad 17 breaks bank conflicts)
#define LG(w_, b_, j_) smemf[((w_)*64 + (b_))*17 + (j_)]

struct ScanParams {
    const int* y;
    const bf16_t *emb16, *Wc1, *Wc2;
    const float *bcat1, *bcat2;
    bf16_t *h1, *h2, *h2all;
    unsigned* bar;    // 64 flags, 32-uint (128B) stride
};

#define SPER (T_ + 1)   // 257 periods
#define NBLK 64
#define FSTRIDE 32      // uints between flags (128B)

__global__ __launch_bounds__(512, 2) void scan_kernel(ScanParams P)
{
    __shared__ __align__(16) float smemf[8704];
    const int bx = blockIdx.x, tid = threadIdx.x;
    const size_t BH = (size_t)B_ * H_;
    const int lane = tid & 63, w = tid >> 6, ml = lane & 15, quad = lane >> 4;
    const int g = w & 3, kh = w >> 2;
    const int isL1 = (bx < 32);
    const int jblk = isL1 ? bx : (bx - 32);
    const int j0 = jblk * 16;

    // ---- fence-proof invariants in registers ----
    const bf16_t* Wcat = isL1 ? P.Wc1 : P.Wc2;
    const float*  bct  = isL1 ? P.bcat1 : P.bcat2;
    const bf16_t* browg = Wcat + (size_t)(g*512 + j0 + ml) * 1024 + (size_t)kh * 512;
    short8 wfrag[16];
    #pragma unroll
    for (int i = 0; i < 16; ++i) wfrag[i] = ld8(browg + i*32 + quad*8);

    const int jj = tid & 15, b0 = tid >> 4;   // cell-phase mapping, fixed per thread
    const int j = j0 + jj;
    const float bi  = bct[j],        bff = bct[512 + j];
    const float bg  = bct[1024 + j], bo  = bct[1536 + j];
    float creg0 = 0.f, creg1 = 0.f;           // c-state, register-resident for whole scan

    for (int p = 0; p < SPER; ++p){
        const int t = isL1 ? p : (p - 1);
        if (t >= 0 && t < T_){
            const bf16_t* h_in  = (isL1 ? P.h1 : P.h2) + (size_t)((t - 1) & 1) * BH;
            bf16_t*       h_out = (isL1 ? P.h1 : P.h2) + (size_t)(t & 1) * BH;
            const bf16_t* x_h1  = P.h1 + (size_t)(t & 1) * BH;   // LSTM2 x-input = h1(t)

            // ---- MFMA phase ----
            const bf16_t* rA[4];
            #pragma unroll
            for (int mi = 0; mi < 4; ++mi){
                int b = mi*16 + ml;
                if (kh == 0){
                    if (isL1){
                        int tok = (t == 0) ? 0 : P.y[b * T_ + (t - 1)];   // SOS=0
                        rA[mi] = P.emb16 + (size_t)tok * 512;
                    } else {
                        rA[mi] = x_h1 + (size_t)b * 512;
                    }
                } else {
                    rA[mi] = h_in + (size_t)b * 512;
                }
            }
            floatx4 acc[4];
            #pragma unroll
            for (int mi = 0; mi < 4; ++mi) acc[mi] = (floatx4){0.f, 0.f, 0.f, 0.f};
            #pragma unroll
            for (int ks16 = 0; ks16 < 16; ++ks16){     // fully unrolled -> wfrag stays in VGPRs
                int ko = ks16*32 + quad*8;
                short8 bf = wfrag[ks16];
                #pragma unroll
                for (int mi = 0; mi < 4; ++mi)
                    acc[mi] = mfma16(ld8(rA[mi] + ko), bf, acc[mi]);
            }
            #pragma unroll
            for (int mi = 0; mi < 4; ++mi)
                #pragma unroll
                for (int r = 0; r < 4; ++r)
                    LG(w, mi*16 + quad*4 + r, ml) = acc[mi][r];
            __syncthreads();
            // ---- cell phase: 512 threads x 2 cells (64 b x 16 j) ----
            {
                int b = b0;
                float gi = LG(0, b, jj) + LG(4, b, jj) + bi;
                float gf = LG(1, b, jj) + LG(5, b, jj) + bff;
                float gg = LG(2, b, jj) + LG(6, b, jj) + bg;
                float go = LG(3, b, jj) + LG(7, b, jj) + bo;
                float cn = sigm(gf) * creg0 + sigm(gi) * tanh_(gg);
                float hn = sigm(go) * tanh_(cn);
                creg0 = cn;
                bf16_t hb = f2bf(hn);
                h_out[(size_t)b * 512 + j] = hb;
                if (!isL1) P.h2all[((size_t)b * T_ + t) * 512 + j] = hb;
            }
            {
                int b = b0 + 32;
                float gi = LG(0, b, jj) + LG(4, b, jj) + bi;
                float gf = LG(1, b, jj) + LG(5, b, jj) + bff;
                float gg = LG(2, b, jj) + LG(6, b, jj) + bg;
                float go = LG(3, b, jj) + LG(7, b, jj) + bo;
                float cn = sigm(gf) * creg1 + sigm(gi) * tanh_(gg);
                float hn = sigm(go) * tanh_(cn);
                creg1 = cn;
                bf16_t hb = f2bf(hn);
                h_out[(size_t)b * 512 + j] = hb;
                if (!isL1) P.h2all[((size_t)b * T_ + t) * 512 + j] = hb;
            }
        }
        // ---- distributed-flag grid barrier (round-5-proven protocol, unchanged) ----
        __syncthreads();   // block stores drained (compiler emits vmcnt(0) before s_barrier)
        if (tid < NBLK){
            if (tid == 0)
                __hip_atomic_fetch_add(&P.bar[(size_t)bx * FSTRIDE], 1u,
                                       __ATOMIC_RELEASE, __HIP_MEMORY_SCOPE_AGENT);
            // lane i polls block i's flag; wave proceeds when every lane's flag reached p+1
            while (__hip_atomic_load(&P.bar[(size_t)tid * FSTRIDE],
                                     __ATOMIC_RELAXED, __HIP_MEMORY_SCOPE_AGENT)
                   < (unsigned)(p + 1))
                __builtin_amdgcn_s_sleep(1);
            __threadfence();   // acquire: invalidate stale L1/L2 before next period's reads
        }
        __syncthreads();
    }
}

// ---------- batched post-scan stages (fully parallel over all 16384 (b,t) rows) ----------

// raw[b*T+t][s] = (h2all[b*T+t] . k2[b][s] + kb[b][s]) / 16;  per batch: M=256, N=512, K=512
__global__ __launch_bounds__(256) void scores_kernel(
    const bf16_t* __restrict__ h2all, const bf16_t* __restrict__ k216,
    const float* __restrict__ kb, float* __restrict__ raw)
{
    const int tid = threadIdx.x, lane = tid & 63, wv = tid >> 6, ml = lane & 15, quad = lane >> 4;
    const int nt = blockIdx.x, mt = blockIdx.y, b = blockIdx.z;
    const int n = nt*64 + wv*16 + ml;            // s
    const bf16_t* brow = k216 + ((size_t)b*512 + n) * 512;
    const bf16_t* rA[4];
    #pragma unroll
    for (int mi = 0; mi < 4; ++mi)
        rA[mi] = h2all + ((size_t)b*T_ + mt*64 + mi*16 + ml) * 512;
    floatx4 acc[4];
    #pragma unroll
    for (int mi = 0; mi < 4; ++mi) acc[mi] = (floatx4){0.f, 0.f, 0.f, 0.f};
    mfma_kloop(rA, brow, 512, quad, acc);
    const float kbn = kb[(size_t)b*512 + n];
    #pragma unroll
    for (int mi = 0; mi < 4; ++mi)
        #pragma unroll
        for (int r = 0; r < 4; ++r){
            int m = mt*64 + mi*16 + quad*4 + r;  // t
            raw[((size_t)b*T_ + m)*512 + n] = (acc[mi][r] + kbn) * 0.0625f;
        }
}

// softmax over s for each of the 16384 rows; writes out_attn (f32) and attn split hi/lo bf16
// (hi+lo two-term split keeps ctx accumulation at f32-attn accuracy through the bf16 MFMA).
__global__ __launch_bounds__(512) void softmax_kernel(
    const float* __restrict__ raw, float* __restrict__ out_attn,
    bf16_t* __restrict__ attnb, bf16_t* __restrict__ attnlo)
{
    __shared__ float red[16];
    const int tid = threadIdx.x;
    const size_t r = blockIdx.x;
    float sc = raw[r*512 + tid];
    float mx = sc;
    #pragma unroll
    for (int o = 32; o > 0; o >>= 1) mx = fmaxf(mx, __shfl_xor(mx, o, 64));
    if ((tid & 63) == 0) red[tid >> 6] = mx;
    __syncthreads();
    float gmax = red[0];
    #pragma unroll
    for (int i = 1; i < 8; ++i) gmax = fmaxf(gmax, red[i]);
    float e = __expf(sc - gmax);
    float sm = e;
    #pragma unroll
    for (int o = 32; o > 0; o >>= 1) sm += __shfl_xor(sm, o, 64);
    if ((tid & 63) == 0) red[8 + (tid >> 6)] = sm;
    __syncthreads();
    float tot = red[8];
    #pragma unroll
    for (int i = 1; i < 8; ++i) tot += red[8 + i];
    float attn = e / tot;
    out_attn[r*512 + tid] = attn;
    bf16_t hi = f2bf(attn);
    attnb [r*512 + tid] = hi;
    attnlo[r*512 + tid] = f2bf(attn - bf2f(hi));
}

// ctx[b*T+t][e] = sum_s attn[b,t,s] * v[b,s,e];  A = attn hi/lo rows, B-rows = vT[b][e][:]
__global__ __launch_bounds__(256) void ctx_kernel(
    const bf16_t* __restrict__ attnb, const bf16_t* __restrict__ attnlo,
    const bf16_t* __restrict__ vT16, bf16_t* __restrict__ ctxb)
{
    const int tid = threadIdx.x, lane = tid & 63, wv = tid >> 6, ml = lane & 15, quad = lane >> 4;
    const int nt = blockIdx.x, mt = blockIdx.y, b = blockIdx.z;
    const int n = nt*64 + wv*16 + ml;            // e
    const bf16_t* brow = vT16 + ((size_t)b*512 + n) * 512;
    const bf16_t* rA[4]; const bf16_t* rAlo[4];
    #pragma unroll
    for (int mi = 0; mi < 4; ++mi){
        size_t row = (size_t)b*T_ + mt*64 + mi*16 + ml;
        rA[mi]   = attnb  + row * 512;
        rAlo[mi] = attnlo + row * 512;
    }
    floatx4 acc[4];
    #pragma unroll
    for (int mi = 0; mi < 4; ++mi) acc[mi] = (floatx4){0.f, 0.f, 0.f, 0.f};
    mfma_kloop(rA,   brow, 512, quad, acc);
    mfma_kloop(rAlo, brow, 512, quad, acc);
    #pragma unroll
    for (int mi = 0; mi < 4; ++mi)
        #pragma unroll
        for (int r = 0; r < 4; ++r){
            int m = mt*64 + mi*16 + quad*4 + r;  // t
            ctxb[((size_t)b*T_ + m)*512 + n] = f2bf(acc[mi][r]);
        }
}

// hid[m][n] = relu([h2all|ctx](m,:) . W1row(n,:) + b1[n]);  M=16384, N=512, K=1024 (two halves)
__global__ __launch_bounds__(512) void hid_kernel(
    const bf16_t* __restrict__ h2all, const bf16_t* __restrict__ ctxb,
    const bf16_t* __restrict__ W116, const float* __restrict__ b1, bf16_t* __restrict__ hid)
{
    const int tid = threadIdx.x, lane = tid & 63, w = tid >> 6, ml = lane & 15, quad = lane >> 4;
    const int nb = blockIdx.x, mb = blockIdx.y;
    const int n = nb*128 + w*16 + ml;
    const bf16_t* brow = W116 + (size_t)n * 1024;
    const bf16_t* rA[4]; const bf16_t* rC[4];
    #pragma unroll
    for (int mi = 0; mi < 4; ++mi){
        size_t m = (size_t)(mb*64 + mi*16 + ml);
        rA[mi] = h2all + m * 512;
        rC[mi] = ctxb  + m * 512;
    }
    floatx4 acc[4];
    #pragma unroll
    for (int mi = 0; mi < 4; ++mi) acc[mi] = (floatx4){0.f, 0.f, 0.f, 0.f};
    mfma_kloop(rA, brow,       512, quad, acc);
    mfma_kloop(rC, brow + 512, 512, quad, acc);
    const float bias = b1[n];
    #pragma unroll
    for (int mi = 0; mi < 4; ++mi)
        #pragma unroll
        for (int r = 0; r < 4; ++r){
            int m = mb*64 + mi*16 + quad*4 + r;
            hid[(size_t)m*512 + n] = f2bf(fmaxf(acc[mi][r] + bias, 0.f));
        }
}

// out_logits[m][n] = hid(m,:) . emb(n,:) + bcls[n];  M=16384, N=1024(pad of 1000), K=512
__global__ __launch_bounds__(512) void logits_kernel(
    const bf16_t* __restrict__ hid, const bf16_t* __restrict__ emb16,
    const float* __restrict__ bcls, float* __restrict__ out_logits)
{
    const int tid = threadIdx.x, lane = tid & 63, w = tid >> 6, ml = lane & 15, quad = lane >> 4;
    const int nb = blockIdx.x, mb = blockIdx.y;
    const int n = nb*128 + w*16 + ml;
    const bf16_t* brow = emb16 + (size_t)n * 512;
    const bf16_t* rA[4];
    #pragma unroll
    for (int mi = 0; mi < 4; ++mi) rA[mi] = hid + (size_t)(mb*64 + mi*16 + ml) * 512;
    floatx4 acc[4];
    #pragma unroll
    for (int mi = 0; mi < 4; ++mi) acc[mi] = (floatx4){0.f, 0.f, 0.f, 0.f};
    mfma_kloop(rA, brow, 512, quad, acc);
    if (n < V_){
        const float bias = bcls[n];
        #pragma unroll
        for (int mi = 0; mi < 4; ++mi)
            #pragma unroll
            for (int r = 0; r < 4; ++r){
                int m = mb*64 + mi*16 + quad*4 + r;
                out_logits[(size_t)m * V_ + n] = acc[mi][r] + bias;
            }
    }
}

// ---------------------------------------------------------------------------
extern "C" void kernel_launch(void* const* d_in, const int* in_sizes, int n_in,
                              void* d_out, int out_size, void* d_ws, size_t ws_size,
                              hipStream_t stream)
{
    const float* enc  = (const float*)d_in[0];
    const int*   y    = (const int*)  d_in[1];
    const float* Wemb = (const float*)d_in[2];
    const float* Wih1 = (const float*)d_in[3];  const float* bih1 = (const float*)d_in[4];
    const float* Whh1 = (const float*)d_in[5];  const float* bhh1 = (const float*)d_in[6];
    const float* Wih2 = (const float*)d_in[7];  const float* bih2 = (const float*)d_in[8];
    const float* Whh2 = (const float*)d_in[9];  const float* bhh2 = (const float*)d_in[10];
    const float* Wq   = (const float*)d_in[11]; const float* bq   = (const float*)d_in[12];
    const float* Wk   = (const float*)d_in[13]; const float* bk   = (const float*)d_in[14];
    const float* Wv   = (const float*)d_in[15]; const float* bv   = (const float*)d_in[16];
    const float* W1   = (const float*)d_in[17]; const float* b1   = (const float*)d_in[18];
    const float* bcls = (const float*)d_in[19];

    float* outF = (float*)d_out;
    float* out_logits = outF;
    float* out_attn   = outF + (size_t)B_ * T_ * V_;

    // workspace carve (256B aligned). Peak ~96 MB via aliasing:
    //  Region A (33.5MB): enc16 -> k216 -> attn hi/lo
    //  Region B (16.8MB): kq16 -> h2all
    //  Region C (33.5MB): vT   -> hid
    //  out_logits region (65.5MB) doubles as scratch: raw scores [0,33.5) then ctxb [33.5,50.3)
    size_t off = 0;
    char* wsb = (char*)d_ws;
    auto carve = [&](size_t bytes) -> void* {
        void* p = wsb + off;
        off += (bytes + 255) & ~(size_t)255;
        return p;
    };
    bf16_t* enc16 = (bf16_t*)carve((size_t)B_*S_*E_*2);     // Region A
    bf16_t* k216  = enc16;
    bf16_t* attnb = enc16;                                   // 16.8MB
    bf16_t* attnlo= enc16 + (size_t)B_*T_*S_;                // +16.8MB = 33.5MB exact
    bf16_t* kq16  = (bf16_t*)carve((size_t)B_*S_*KQ_*2);    // Region B
    bf16_t* h2all = kq16;                                    // B*T*H*2 = 16.8MB exact
    bf16_t* vT16  = (bf16_t*)carve((size_t)B_*S_*E_*2);     // Region C
    bf16_t* hid   = vT16;                                    // 16.8MB <= 33.5MB
    bf16_t* Wc1   = (bf16_t*)carve((size_t)2048*1024*2);
    bf16_t* Wc2   = (bf16_t*)carve((size_t)2048*1024*2);
    bf16_t* emb16 = (bf16_t*)carve((size_t)1024*512*2);     // padded to 1024 rows
    bf16_t* W116  = (bf16_t*)carve((size_t)512*1024*2);
    bf16_t* WqT16 = (bf16_t*)carve((size_t)512*256*2);
    bf16_t* Wkv16 = (bf16_t*)carve((size_t)768*512*2);
    float*  bcat1 = (float*) carve(2048*4);
    float*  bcat2 = (float*) carve(2048*4);
    float*  bkv   = (float*) carve(768*4);
    float*  kb    = (float*) carve((size_t)B_*S_*4);        // 128 KB
    bf16_t* h1b   = (bf16_t*)carve((size_t)2*B_*H_*2);      // ping-pong
    bf16_t* h2b   = (bf16_t*)carve((size_t)2*B_*H_*2);
    unsigned* bar = (unsigned*)carve(NBLK * FSTRIDE * 4);    // 64 distributed flags, 128B apart

    float*  raw   = out_logits;                              // [16384][512] f32 scratch in out region
    bf16_t* ctxb  = (bf16_t*)((char*)out_logits + (size_t)B_*T_*S_*4);  // next 16.8MB of out region

    // zero recurrent state + barrier flags (ws is poisoned before every call)
    // (c-state is now register-resident in scan_kernel — no global c buffers)
    hipMemsetAsync(h1b, 0, (size_t)2*B_*H_*2, stream);
    hipMemsetAsync(h2b, 0, (size_t)2*B_*H_*2, stream);
    hipMemsetAsync(bar, 0, NBLK * FSTRIDE * 4, stream);

    // setup: convert weights/enc, project k/v (v transposed), fold Wq into k2, bq into kb
    convert_kernel<<<8192, 256, 0, stream>>>(enc, Wemb, Wih1, Whh1, Wih2, Whh2, Wq, Wk, Wv, W1,
                                             bih1, bhh1, bih2, bhh2, bk, bv,
                                             Wc1, Wc2, emb16, W116, WqT16, Wkv16, enc16,
                                             bcat1, bcat2, bkv);
    gemm_kv_kernel<<<dim3(512, 12), 256, 0, stream>>>(enc16, Wkv16, bkv, kq16, vT16);
    gemm_k2_kernel<<<dim3(512, 8), 256, 0, stream>>>(kq16, WqT16, k216);
    kbias_kernel<<<128, 256, 0, stream>>>(kq16, bq, kb);

    // sequential part: ONLY the LSTM chain (64-block cooperative kernel, distributed-flag barrier,
    // weights/biases/c-state register-resident across all 257 periods)
    ScanParams sp;
    sp.y = y; sp.emb16 = emb16; sp.Wc1 = Wc1; sp.Wc2 = Wc2;
    sp.bcat1 = bcat1; sp.bcat2 = bcat2;
    sp.h1 = h1b; sp.h2 = h2b; sp.h2all = h2all;
    sp.bar = bar;
    void* kargs[] = { (void*)&sp };
    hipLaunchCooperativeKernel((const void*)scan_kernel, dim3(64), dim3(512), kargs, 0, stream);

    // batch-parallel tail: scores -> softmax -> ctx -> hid -> logits
    scores_kernel <<<dim3(8, 4, B_), 256, 0, stream>>>(h2all, k216, kb, raw);
    softmax_kernel<<<(size_t)B_*T_, 512, 0, stream>>>(raw, out_attn, attnb, attnlo);
    ctx_kernel    <<<dim3(8, 4, B_), 256, 0, stream>>>(attnb, attnlo, vT16, ctxb);
    hid_kernel    <<<dim3(4, 256), 512, 0, stream>>>(h2all, ctxb, W116, b1, hid);
    logits_kernel <<<dim3(8, 256), 512, 0, stream>>>(hid, emb16, bcls, out_logits);
}